// Round 3
// baseline (347.320 us; speedup 1.0000x reference)
//
#include <hip/hip_runtime.h>
#include <math.h>

typedef __bf16 bf16;
typedef __attribute__((ext_vector_type(8))) __bf16 bf16x8;
typedef __attribute__((ext_vector_type(4))) __bf16 bf16x4;
typedef __attribute__((ext_vector_type(4))) float f32x4;
typedef __attribute__((ext_vector_type(16))) float f32x16;

typedef __attribute__((address_space(1))) const void gvoid;
typedef __attribute__((address_space(3))) void lvoid;
#define GLL(g, l) __builtin_amdgcn_global_load_lds((gvoid*)(g), (lvoid*)(l), 16, 0, 0)
#define MFMA(a, b, c) __builtin_amdgcn_mfma_f32_16x16x32_bf16((a), (b), (c), 0, 0, 0)
#define MFMA32(a, b, c) __builtin_amdgcn_mfma_f32_32x32x16_bf16((a), (b), (c), 0, 0, 0)

__device__ __forceinline__ int swz128(int row, int kb) { return kb ^ ((row & 7) << 4); }

// ---------------- prep: W1 [1024][512] -> W1t bf16 [512][1024]; W2 [512][256] -> W2t [256][512]
__global__ __launch_bounds__(256) void prep_w(const float* __restrict__ W1,
                                              const float* __restrict__ W2,
                                              bf16* __restrict__ W1t, bf16* __restrict__ W2t) {
  const int t = blockIdx.x * 256 + threadIdx.x;
  if (t < 512 * 1024) {
    const int h = t & 511, k = t >> 9;
    W1t[h * 1024 + k] = (bf16)W1[k * 512 + h];
  } else {
    const int u = t - 512 * 1024;
    const int e = u & 255, k = u >> 8;
    W2t[e * 512 + k] = (bf16)W2[k * 256 + e];
  }
}

// ---------------- prep: bank fp32 [16384][256] -> BB = -2*bank (bf16) + m2 (fp32)
__global__ __launch_bounds__(256) void prep_bank(const float* __restrict__ bank,
                                                 bf16* __restrict__ BB, float* __restrict__ m2) {
  const int tid = threadIdx.x, lane = tid & 63, w = tid >> 6;
  const int row = blockIdx.x * 4 + w;
  const float4 v = *reinterpret_cast<const float4*>(bank + (size_t)row * 256 + lane * 4);
  float s = v.x * v.x + v.y * v.y + v.z * v.z + v.w * v.w;
#pragma unroll
  for (int off = 1; off < 64; off <<= 1) s += __shfl_xor(s, off);
  bf16x4 p;
  p[0] = (bf16)(-2.f * v.x); p[1] = (bf16)(-2.f * v.y);
  p[2] = (bf16)(-2.f * v.z); p[3] = (bf16)(-2.f * v.w);
  *reinterpret_cast<bf16x4*>(BB + (size_t)row * 256 + lane * 4) = p;
  if (lane == 0) m2[row] = s;
}

// ---------------- mlp1: H[32768][512] = relu(F @ W1 + b1), bf16 out
__global__ __launch_bounds__(512, 2) void mlp1_kernel(const float* __restrict__ F,
                                                      const bf16* __restrict__ W1t,
                                                      const float* __restrict__ b1,
                                                      bf16* __restrict__ H) {
  __shared__ __align__(16) char smem[81920];
  char* sA = smem;          // F chunk bf16 [128 rows][128B], swizzled
  char* sB = smem + 16384;  // W1t chunk [512 n][128B], swizzled

  const int tid = threadIdx.x;
  const int w = tid >> 6, lane = tid & 63;
  const int wm = w >> 2, wn = w & 3;
  const int lr = lane & 15, lk = lane >> 4;
  const size_t r0 = (size_t)blockIdx.x * 128;

  f32x4 acc[4][8];
  const f32x4 z = {0.f, 0.f, 0.f, 0.f};
#pragma unroll
  for (int m = 0; m < 4; ++m)
#pragma unroll
    for (int n = 0; n < 8; ++n) acc[m][n] = z;

  for (int kc = 0; kc < 16; ++kc) {
    // stage F chunk (fp32 -> bf16, swizzled ds_write)
    {
      const int fr = tid >> 2, kg = (tid & 3) * 16;
      const float* fsrc = F + (r0 + fr) * 1024 + kc * 64 + kg;
      const float4 f0 = *reinterpret_cast<const float4*>(fsrc);
      const float4 f1 = *reinterpret_cast<const float4*>(fsrc + 4);
      const float4 f2 = *reinterpret_cast<const float4*>(fsrc + 8);
      const float4 f3 = *reinterpret_cast<const float4*>(fsrc + 12);
      bf16x8 p0, p1;
      p0[0] = (bf16)f0.x; p0[1] = (bf16)f0.y; p0[2] = (bf16)f0.z; p0[3] = (bf16)f0.w;
      p0[4] = (bf16)f1.x; p0[5] = (bf16)f1.y; p0[6] = (bf16)f1.z; p0[7] = (bf16)f1.w;
      p1[0] = (bf16)f2.x; p1[1] = (bf16)f2.y; p1[2] = (bf16)f2.z; p1[3] = (bf16)f2.w;
      p1[4] = (bf16)f3.x; p1[5] = (bf16)f3.y; p1[6] = (bf16)f3.z; p1[7] = (bf16)f3.w;
      const int bb = kg * 2;
      *(bf16x8*)(sA + fr * 128 + swz128(fr, bb)) = p0;
      *(bf16x8*)(sA + fr * 128 + swz128(fr, bb + 16)) = p1;
    }
    // stage W1t chunk via global_load_lds (pre-swizzled source)
#pragma unroll
    for (int i = 0; i < 8; ++i) {
      const int o = (w * 8 + i) * 1024 + lane * 16;
      const int n = o >> 7, b = o & 127;
      GLL((const char*)W1t + n * 2048 + kc * 128 + swz128(n, b), sB + (w * 8 + i) * 1024);
    }
    __syncthreads();
#pragma unroll
    for (int ks = 0; ks < 2; ++ks) {
      bf16x8 av[4];
#pragma unroll
      for (int Mt = 0; Mt < 4; ++Mt) {
        const int row = wm * 64 + Mt * 16 + lr;
        av[Mt] = *(const bf16x8*)(sA + row * 128 + swz128(row, ks * 64 + lk * 16));
      }
#pragma unroll
      for (int Nt = 0; Nt < 8; ++Nt) {
        const int n = wn * 128 + Nt * 16 + lr;
        const bf16x8 bv = *(const bf16x8*)(sB + n * 128 + swz128(n, ks * 64 + lk * 16));
#pragma unroll
        for (int Mt = 0; Mt < 4; ++Mt) acc[Mt][Nt] = MFMA(av[Mt], bv, acc[Mt][Nt]);
      }
    }
    __syncthreads();
  }
  // epilogue: bias + relu + bf16 store
#pragma unroll
  for (int Nt = 0; Nt < 8; ++Nt) {
    const int col = wn * 128 + Nt * 16 + lr;
    const float bias = b1[col];
#pragma unroll
    for (int Mt = 0; Mt < 4; ++Mt) {
      const size_t rowb = r0 + wm * 64 + Mt * 16 + lk * 4;
#pragma unroll
      for (int q = 0; q < 4; ++q)
        H[(rowb + q) * 512 + col] = (bf16)fmaxf(acc[Mt][Nt][q] + bias, 0.f);
    }
  }
}

// ---------------- mlp2: PROJ[32768][256] bf16 = H @ W2 + b2 ; X2[32768] fp32
__global__ __launch_bounds__(512, 2) void mlp2_kernel(const bf16* __restrict__ H,
                                                      const bf16* __restrict__ W2t,
                                                      const float* __restrict__ b2,
                                                      bf16* __restrict__ PROJ,
                                                      float* __restrict__ X2) {
  __shared__ __align__(16) char smem[51200];
  char* sA = smem;                        // H chunk [128][128B] swizzled
  char* sB = smem + 16384;                // W2t chunk [256][128B] swizzled
  float* sX2 = (float*)(smem + 49152);    // [4][128]

  const int tid = threadIdx.x;
  const int w = tid >> 6, lane = tid & 63;
  const int wm = w >> 2, wn = w & 3;
  const int lr = lane & 15, lk = lane >> 4;
  const size_t r0 = (size_t)blockIdx.x * 128;

  f32x4 acc[4][4];
  const f32x4 z = {0.f, 0.f, 0.f, 0.f};
#pragma unroll
  for (int m = 0; m < 4; ++m)
#pragma unroll
    for (int n = 0; n < 4; ++n) acc[m][n] = z;

  for (int kc = 0; kc < 8; ++kc) {
#pragma unroll
    for (int i = 0; i < 2; ++i) {
      const int o = (w * 2 + i) * 1024 + lane * 16;
      const int row = o >> 7, b = o & 127;
      GLL((const char*)H + (r0 + row) * 1024 + kc * 128 + swz128(row, b), sA + (w * 2 + i) * 1024);
    }
#pragma unroll
    for (int i = 0; i < 4; ++i) {
      const int o = (w * 4 + i) * 1024 + lane * 16;
      const int n = o >> 7, b = o & 127;
      GLL((const char*)W2t + n * 1024 + kc * 128 + swz128(n, b), sB + (w * 4 + i) * 1024);
    }
    __syncthreads();
#pragma unroll
    for (int ks = 0; ks < 2; ++ks) {
      bf16x8 av[4];
#pragma unroll
      for (int Mt = 0; Mt < 4; ++Mt) {
        const int row = wm * 64 + Mt * 16 + lr;
        av[Mt] = *(const bf16x8*)(sA + row * 128 + swz128(row, ks * 64 + lk * 16));
      }
#pragma unroll
      for (int Nt = 0; Nt < 4; ++Nt) {
        const int n = wn * 64 + Nt * 16 + lr;
        const bf16x8 bv = *(const bf16x8*)(sB + n * 128 + swz128(n, ks * 64 + lk * 16));
#pragma unroll
        for (int Mt = 0; Mt < 4; ++Mt) acc[Mt][Nt] = MFMA(av[Mt], bv, acc[Mt][Nt]);
      }
    }
    __syncthreads();
  }
  // epilogue: +b2, store bf16 proj, accumulate x2
  float x2p[4][4];
#pragma unroll
  for (int m = 0; m < 4; ++m)
#pragma unroll
    for (int q = 0; q < 4; ++q) x2p[m][q] = 0.f;
#pragma unroll
  for (int Nt = 0; Nt < 4; ++Nt) {
    const int col = wn * 64 + Nt * 16 + lr;
    const float bias = b2[col];
#pragma unroll
    for (int Mt = 0; Mt < 4; ++Mt) {
      const size_t rowb = r0 + wm * 64 + Mt * 16 + lk * 4;
#pragma unroll
      for (int q = 0; q < 4; ++q) {
        const float p = acc[Mt][Nt][q] + bias;
        PROJ[(rowb + q) * 256 + col] = (bf16)p;
        x2p[Mt][q] += p * p;
      }
    }
  }
#pragma unroll
  for (int Mt = 0; Mt < 4; ++Mt)
#pragma unroll
    for (int q = 0; q < 4; ++q) {
      float v = x2p[Mt][q];
      v += __shfl_xor(v, 1); v += __shfl_xor(v, 2);
      v += __shfl_xor(v, 4); v += __shfl_xor(v, 8);
      x2p[Mt][q] = v;
    }
  __syncthreads();
  if (lr == 0) {
#pragma unroll
    for (int Mt = 0; Mt < 4; ++Mt)
#pragma unroll
      for (int q = 0; q < 4; ++q)
        sX2[wn * 128 + wm * 64 + Mt * 16 + lk * 4 + q] = x2p[Mt][q];
  }
  __syncthreads();
  if (tid < 128)
    X2[r0 + tid] = sX2[tid] + sX2[128 + tid] + sX2[256 + tid] + sX2[384 + tid];
}

// ---------------- dist: out[r] = sqrt(max(x2[r] + min_m(m2[m] - 2*proj[r].bank[m]), 0))
// 32x32x16 MFMA; BB holds -2*bank; acc initialized with m2 -> epilogue is pure fmin.
__global__ __launch_bounds__(512, 2) void dist_kernel(const bf16* __restrict__ PROJ,
                                                      const bf16* __restrict__ BB,
                                                      const float* __restrict__ m2,
                                                      const float* __restrict__ X2,
                                                      float* __restrict__ out) {
  __shared__ __align__(16) char smem[133120];
  char* buf0 = smem;
  char* buf1 = smem + 65536;
  float* minbuf = (float*)(smem + 131072);  // [4][128]

  const int tid = threadIdx.x;
  const int w = tid >> 6, lane = tid & 63;
  const int wm = w >> 2, wn = w & 3;       // 2 row-groups x 4 bank-groups
  const int l31 = lane & 31, hi = lane >> 5;
  const size_t r0 = (size_t)blockIdx.x * 128;

  // A fragments (proj) in registers for the whole bank stream:
  // wave covers rows [wm*64, wm*64+64): two 32-row MFMA blocks.
  bf16x8 A0[16], A1[16];
#pragma unroll
  for (int ks = 0; ks < 16; ++ks) {
    const size_t rowb = r0 + wm * 64 + l31;
    A0[ks] = *(const bf16x8*)(PROJ + rowb * 256 + ks * 16 + hi * 8);
    A1[ks] = *(const bf16x8*)(PROJ + (rowb + 32) * 256 + ks * 16 + hi * 8);
  }

  // stage tile 0 (banks 0..127, full K) into buf0
#pragma unroll
  for (int i = 0; i < 8; ++i) {
    const int o = (w * 8 + i) * 1024 + lane * 16;
    const int n = o >> 9, b = o & 511;
    GLL((const char*)BB + (size_t)n * 512 + (b ^ ((n & 7) << 4)), buf0 + (w * 8 + i) * 1024);
  }

  float m2cur = m2[wn * 32 + l31];

  f32x16 minv0, minv1;
#pragma unroll
  for (int r = 0; r < 16; ++r) { minv0[r] = 3.0e38f; minv1[r] = 3.0e38f; }

  __syncthreads();

  const int nb = wn * 32 + l31;        // bank row within tile, this lane's column
  const int swz = (nb & 7) << 4;

  for (int t = 0; t < 128; ++t) {
    char* cur = (t & 1) ? buf1 : buf0;
    char* nxt = (t & 1) ? buf0 : buf1;
    float m2nxt = 0.f;
    if (t < 127) {
#pragma unroll
      for (int i = 0; i < 8; ++i) {
        const int o = (w * 8 + i) * 1024 + lane * 16;
        const int n = o >> 9, b = o & 511;
        GLL((const char*)BB + ((size_t)(t + 1) * 128 + n) * 512 + (b ^ ((n & 7) << 4)),
            nxt + (w * 8 + i) * 1024);
      }
      m2nxt = m2[(t + 1) * 128 + nb];
    }
    // acc starts at m2[col]; BB = -2*bank, so acc ends at m2 - 2*<proj,bank>
    f32x16 acc0, acc1;
#pragma unroll
    for (int r = 0; r < 16; ++r) { acc0[r] = m2cur; acc1[r] = m2cur; }
    const char* base = cur + nb * 512;
#pragma unroll
    for (int g = 0; g < 4; ++g) {
      bf16x8 bv[4];
#pragma unroll
      for (int j = 0; j < 4; ++j)
        bv[j] = *(const bf16x8*)(base + (((g * 4 + j) * 32 + hi * 16) ^ swz));
#pragma unroll
      for (int j = 0; j < 4; ++j) {
        acc0 = MFMA32(A0[g * 4 + j], bv[j], acc0);
        acc1 = MFMA32(A1[g * 4 + j], bv[j], acc1);
      }
    }
#pragma unroll
    for (int r = 0; r < 16; ++r) {
      minv0[r] = fminf(minv0[r], acc0[r]);
      minv1[r] = fminf(minv1[r], acc1[r]);
    }
    m2cur = m2nxt;
    __syncthreads();
  }

  // reduce min across the 32 bank-column lanes (rows differ by hi, so reduce within halves)
#pragma unroll
  for (int r = 0; r < 16; ++r) {
    float v0 = minv0[r], v1 = minv1[r];
#pragma unroll
    for (int off = 1; off < 32; off <<= 1) {
      v0 = fminf(v0, __shfl_xor(v0, off));
      v1 = fminf(v1, __shfl_xor(v1, off));
    }
    minv0[r] = v0; minv1[r] = v1;
  }
  if (l31 == 0) {
#pragma unroll
    for (int r = 0; r < 16; ++r) {
      const int rowa = (r & 3) + 8 * (r >> 2) + 4 * hi;  // C/D row map, 32x32
      minbuf[wn * 128 + wm * 64 + rowa] = minv0[r];
      minbuf[wn * 128 + wm * 64 + 32 + rowa] = minv1[r];
    }
  }
  __syncthreads();
  if (tid < 128) {
    const float m = fminf(fminf(minbuf[tid], minbuf[128 + tid]),
                          fminf(minbuf[256 + tid], minbuf[384 + tid]));
    const float d2 = X2[r0 + tid] + m;
    out[r0 + tid] = sqrtf(fmaxf(d2, 0.f));
  }
}

extern "C" void kernel_launch(void* const* d_in, const int* in_sizes, int n_in,
                              void* d_out, int out_size, void* d_ws, size_t ws_size,
                              hipStream_t stream) {
  const float* F = (const float*)d_in[0];
  const float* W1 = (const float*)d_in[1];
  const float* b1 = (const float*)d_in[2];
  const float* W2 = (const float*)d_in[3];
  const float* b2 = (const float*)d_in[4];
  const float* bank = (const float*)d_in[5];
  float* out = (float*)d_out;

  char* ws = (char*)d_ws;
  bf16* BB = (bf16*)(ws + 0);            //  8,388,608 B   (-2 * bank, bf16)
  float* m2 = (float*)(ws + 8388608);    //     65,536 B
  bf16* W1t = (bf16*)(ws + 8454144);     //  1,048,576 B
  bf16* W2t = (bf16*)(ws + 9502720);     //    262,144 B
  bf16* H = (bf16*)(ws + 9764864);       // 33,554,432 B
  bf16* PROJ = (bf16*)(ws + 43319296);   // 16,777,216 B
  float* X2 = (float*)(ws + 60096512);   //    131,072 B  -> total 60,227,584 B

  prep_w<<<2560, 256, 0, stream>>>(W1, W2, W1t, W2t);
  prep_bank<<<4096, 256, 0, stream>>>(bank, BB, m2);
  mlp1_kernel<<<256, 512, 0, stream>>>(F, W1t, b1, H);
  mlp2_kernel<<<256, 512, 0, stream>>>(H, W2t, b2, PROJ, X2);
  dist_kernel<<<256, 512, 0, stream>>>(PROJ, BB, m2, X2, out);
}

// Round 4
// 297.750 us; speedup vs baseline: 1.1665x; 1.1665x over previous
//
#include <hip/hip_runtime.h>
#include <math.h>

typedef __bf16 bf16;
typedef __attribute__((ext_vector_type(8))) __bf16 bf16x8;
typedef __attribute__((ext_vector_type(4))) __bf16 bf16x4;
typedef __attribute__((ext_vector_type(4))) float f32x4;

typedef __attribute__((address_space(1))) const void gvoid;
typedef __attribute__((address_space(3))) void lvoid;
#define GLL(g, l) __builtin_amdgcn_global_load_lds((gvoid*)(g), (lvoid*)(l), 16, 0, 0)
#define MFMA(a, b, c) __builtin_amdgcn_mfma_f32_16x16x32_bf16((a), (b), (c), 0, 0, 0)

__device__ __forceinline__ int swz128(int row, int kb) { return kb ^ ((row & 7) << 4); }

// ---------------- prep: W1 [1024][512] -> W1t bf16 [512][1024]; W2 [512][256] -> W2t [256][512]
__global__ __launch_bounds__(256) void prep_w(const float* __restrict__ W1,
                                              const float* __restrict__ W2,
                                              bf16* __restrict__ W1t, bf16* __restrict__ W2t) {
  const int t = blockIdx.x * 256 + threadIdx.x;
  if (t < 512 * 1024) {
    const int h = t & 511, k = t >> 9;
    W1t[h * 1024 + k] = (bf16)W1[k * 512 + h];
  } else {
    const int u = t - 512 * 1024;
    const int e = u & 255, k = u >> 8;
    W2t[e * 512 + k] = (bf16)W2[k * 256 + e];
  }
}

// ---------------- prep: bank fp32 [16384][256] -> BB = -2*bank (bf16) + m2 (fp32)
__global__ __launch_bounds__(256) void prep_bank(const float* __restrict__ bank,
                                                 bf16* __restrict__ BB, float* __restrict__ m2) {
  const int tid = threadIdx.x, lane = tid & 63, w = tid >> 6;
  const int row = blockIdx.x * 4 + w;
  const float4 v = *reinterpret_cast<const float4*>(bank + (size_t)row * 256 + lane * 4);
  float s = v.x * v.x + v.y * v.y + v.z * v.z + v.w * v.w;
#pragma unroll
  for (int off = 1; off < 64; off <<= 1) s += __shfl_xor(s, off);
  bf16x4 p;
  p[0] = (bf16)(-2.f * v.x); p[1] = (bf16)(-2.f * v.y);
  p[2] = (bf16)(-2.f * v.z); p[3] = (bf16)(-2.f * v.w);
  *reinterpret_cast<bf16x4*>(BB + (size_t)row * 256 + lane * 4) = p;
  if (lane == 0) m2[row] = s;
}

// ---------------- mlp1: H[32768][512] = relu(F @ W1 + b1), bf16 out
__global__ __launch_bounds__(512, 2) void mlp1_kernel(const float* __restrict__ F,
                                                      const bf16* __restrict__ W1t,
                                                      const float* __restrict__ b1,
                                                      bf16* __restrict__ H) {
  __shared__ __align__(16) char smem[81920];
  char* sA = smem;          // F chunk bf16 [128 rows][128B], swizzled
  char* sB = smem + 16384;  // W1t chunk [512 n][128B], swizzled

  const int tid = threadIdx.x;
  const int w = tid >> 6, lane = tid & 63;
  const int wm = w >> 2, wn = w & 3;
  const int lr = lane & 15, lk = lane >> 4;
  const size_t r0 = (size_t)blockIdx.x * 128;

  f32x4 acc[4][8];
  const f32x4 z = {0.f, 0.f, 0.f, 0.f};
#pragma unroll
  for (int m = 0; m < 4; ++m)
#pragma unroll
    for (int n = 0; n < 8; ++n) acc[m][n] = z;

  for (int kc = 0; kc < 16; ++kc) {
    // stage F chunk (fp32 -> bf16, swizzled ds_write)
    {
      const int fr = tid >> 2, kg = (tid & 3) * 16;
      const float* fsrc = F + (r0 + fr) * 1024 + kc * 64 + kg;
      const float4 f0 = *reinterpret_cast<const float4*>(fsrc);
      const float4 f1 = *reinterpret_cast<const float4*>(fsrc + 4);
      const float4 f2 = *reinterpret_cast<const float4*>(fsrc + 8);
      const float4 f3 = *reinterpret_cast<const float4*>(fsrc + 12);
      bf16x8 p0, p1;
      p0[0] = (bf16)f0.x; p0[1] = (bf16)f0.y; p0[2] = (bf16)f0.z; p0[3] = (bf16)f0.w;
      p0[4] = (bf16)f1.x; p0[5] = (bf16)f1.y; p0[6] = (bf16)f1.z; p0[7] = (bf16)f1.w;
      p1[0] = (bf16)f2.x; p1[1] = (bf16)f2.y; p1[2] = (bf16)f2.z; p1[3] = (bf16)f2.w;
      p1[4] = (bf16)f3.x; p1[5] = (bf16)f3.y; p1[6] = (bf16)f3.z; p1[7] = (bf16)f3.w;
      const int bb = kg * 2;
      *(bf16x8*)(sA + fr * 128 + swz128(fr, bb)) = p0;
      *(bf16x8*)(sA + fr * 128 + swz128(fr, bb + 16)) = p1;
    }
    // stage W1t chunk via global_load_lds (pre-swizzled source)
#pragma unroll
    for (int i = 0; i < 8; ++i) {
      const int o = (w * 8 + i) * 1024 + lane * 16;
      const int n = o >> 7, b = o & 127;
      GLL((const char*)W1t + n * 2048 + kc * 128 + swz128(n, b), sB + (w * 8 + i) * 1024);
    }
    __syncthreads();
#pragma unroll
    for (int ks = 0; ks < 2; ++ks) {
      bf16x8 av[4];
#pragma unroll
      for (int Mt = 0; Mt < 4; ++Mt) {
        const int row = wm * 64 + Mt * 16 + lr;
        av[Mt] = *(const bf16x8*)(sA + row * 128 + swz128(row, ks * 64 + lk * 16));
      }
#pragma unroll
      for (int Nt = 0; Nt < 8; ++Nt) {
        const int n = wn * 128 + Nt * 16 + lr;
        const bf16x8 bv = *(const bf16x8*)(sB + n * 128 + swz128(n, ks * 64 + lk * 16));
#pragma unroll
        for (int Mt = 0; Mt < 4; ++Mt) acc[Mt][Nt] = MFMA(av[Mt], bv, acc[Mt][Nt]);
      }
    }
    __syncthreads();
  }
  // epilogue: bias + relu + bf16 store
#pragma unroll
  for (int Nt = 0; Nt < 8; ++Nt) {
    const int col = wn * 128 + Nt * 16 + lr;
    const float bias = b1[col];
#pragma unroll
    for (int Mt = 0; Mt < 4; ++Mt) {
      const size_t rowb = r0 + wm * 64 + Mt * 16 + lk * 4;
#pragma unroll
      for (int q = 0; q < 4; ++q)
        H[(rowb + q) * 512 + col] = (bf16)fmaxf(acc[Mt][Nt][q] + bias, 0.f);
    }
  }
}

// ---------------- mlp2: PROJ[32768][256] bf16 = H @ W2 + b2 ; X2[32768] fp32
__global__ __launch_bounds__(512, 2) void mlp2_kernel(const bf16* __restrict__ H,
                                                      const bf16* __restrict__ W2t,
                                                      const float* __restrict__ b2,
                                                      bf16* __restrict__ PROJ,
                                                      float* __restrict__ X2) {
  __shared__ __align__(16) char smem[51200];
  char* sA = smem;                        // H chunk [128][128B] swizzled
  char* sB = smem + 16384;                // W2t chunk [256][128B] swizzled
  float* sX2 = (float*)(smem + 49152);    // [4][128]

  const int tid = threadIdx.x;
  const int w = tid >> 6, lane = tid & 63;
  const int wm = w >> 2, wn = w & 3;
  const int lr = lane & 15, lk = lane >> 4;
  const size_t r0 = (size_t)blockIdx.x * 128;

  f32x4 acc[4][4];
  const f32x4 z = {0.f, 0.f, 0.f, 0.f};
#pragma unroll
  for (int m = 0; m < 4; ++m)
#pragma unroll
    for (int n = 0; n < 4; ++n) acc[m][n] = z;

  for (int kc = 0; kc < 8; ++kc) {
#pragma unroll
    for (int i = 0; i < 2; ++i) {
      const int o = (w * 2 + i) * 1024 + lane * 16;
      const int row = o >> 7, b = o & 127;
      GLL((const char*)H + (r0 + row) * 1024 + kc * 128 + swz128(row, b), sA + (w * 2 + i) * 1024);
    }
#pragma unroll
    for (int i = 0; i < 4; ++i) {
      const int o = (w * 4 + i) * 1024 + lane * 16;
      const int n = o >> 7, b = o & 127;
      GLL((const char*)W2t + n * 1024 + kc * 128 + swz128(n, b), sB + (w * 4 + i) * 1024);
    }
    __syncthreads();
#pragma unroll
    for (int ks = 0; ks < 2; ++ks) {
      bf16x8 av[4];
#pragma unroll
      for (int Mt = 0; Mt < 4; ++Mt) {
        const int row = wm * 64 + Mt * 16 + lr;
        av[Mt] = *(const bf16x8*)(sA + row * 128 + swz128(row, ks * 64 + lk * 16));
      }
#pragma unroll
      for (int Nt = 0; Nt < 4; ++Nt) {
        const int n = wn * 64 + Nt * 16 + lr;
        const bf16x8 bv = *(const bf16x8*)(sB + n * 128 + swz128(n, ks * 64 + lk * 16));
#pragma unroll
        for (int Mt = 0; Mt < 4; ++Mt) acc[Mt][Nt] = MFMA(av[Mt], bv, acc[Mt][Nt]);
      }
    }
    __syncthreads();
  }
  // epilogue: +b2, store bf16 proj, accumulate x2
  float x2p[4][4];
#pragma unroll
  for (int m = 0; m < 4; ++m)
#pragma unroll
    for (int q = 0; q < 4; ++q) x2p[m][q] = 0.f;
#pragma unroll
  for (int Nt = 0; Nt < 4; ++Nt) {
    const int col = wn * 64 + Nt * 16 + lr;
    const float bias = b2[col];
#pragma unroll
    for (int Mt = 0; Mt < 4; ++Mt) {
      const size_t rowb = r0 + wm * 64 + Mt * 16 + lk * 4;
#pragma unroll
      for (int q = 0; q < 4; ++q) {
        const float p = acc[Mt][Nt][q] + bias;
        PROJ[(rowb + q) * 256 + col] = (bf16)p;
        x2p[Mt][q] += p * p;
      }
    }
  }
#pragma unroll
  for (int Mt = 0; Mt < 4; ++Mt)
#pragma unroll
    for (int q = 0; q < 4; ++q) {
      float v = x2p[Mt][q];
      v += __shfl_xor(v, 1); v += __shfl_xor(v, 2);
      v += __shfl_xor(v, 4); v += __shfl_xor(v, 8);
      x2p[Mt][q] = v;
    }
  __syncthreads();
  if (lr == 0) {
#pragma unroll
    for (int Mt = 0; Mt < 4; ++Mt)
#pragma unroll
      for (int q = 0; q < 4; ++q)
        sX2[wn * 128 + wm * 64 + Mt * 16 + lk * 4 + q] = x2p[Mt][q];
  }
  __syncthreads();
  if (tid < 128)
    X2[r0 + tid] = sX2[tid] + sX2[128 + tid] + sX2[256 + tid] + sX2[384 + tid];
}

// ---------------- dist: out[r] = sqrt(max(x2[r] + min_m(m2[m] - 2*proj[r].bank[m]), 0))
// 16x16x32 MFMA (r2 structure); BB = -2*bank; acc init = m2[col]; batched ds_reads +
// setprio'd MFMA clusters; GLL prefetch split across the two half-phases.
__global__ __launch_bounds__(512, 2) void dist_kernel(const bf16* __restrict__ PROJ,
                                                      const bf16* __restrict__ BB,
                                                      const float* __restrict__ m2,
                                                      const float* __restrict__ X2,
                                                      float* __restrict__ out) {
  __shared__ __align__(16) char smem[133120];
  char* buf0 = smem;
  char* buf1 = smem + 65536;
  float* minbuf = (float*)(smem + 131072);  // [4][128]

  const int tid = threadIdx.x;
  const int w = tid >> 6, lane = tid & 63;
  const int wm = w >> 2, wn = w & 3;
  const int lr = lane & 15, lk = lane >> 4;
  const size_t r0 = (size_t)blockIdx.x * 128;

  // A (proj) fragments held in registers for the whole bank stream
  bf16x8 A[4][8];
#pragma unroll
  for (int Mt = 0; Mt < 4; ++Mt)
#pragma unroll
    for (int ks = 0; ks < 8; ++ks) {
      const size_t row = r0 + wm * 64 + Mt * 16 + lr;
      A[Mt][ks] = *(const bf16x8*)(PROJ + row * 256 + ks * 32 + lk * 8);
    }

  // stage tile 0 (banks 0..127, full K) into buf0
#pragma unroll
  for (int i = 0; i < 8; ++i) {
    const int o = (w * 8 + i) * 1024 + lane * 16;
    const int n = o >> 9, b = o & 511;
    GLL((const char*)BB + (size_t)n * 512 + (b ^ ((n & 7) << 4)), buf0 + (w * 8 + i) * 1024);
  }

  const int n0 = wn * 32 + lr;       // this lane's Nt=0 bank row within the tile
  const int swz = (n0 & 7) << 4;     // identical for n0 and n0+16

  float m2c0 = m2[n0];
  float m2c1 = m2[n0 + 16];

  float minv[4][4];
#pragma unroll
  for (int m = 0; m < 4; ++m)
#pragma unroll
    for (int q = 0; q < 4; ++q) minv[m][q] = 3.0e38f;

  __syncthreads();

  for (int t = 0; t < 128; ++t) {
    char* cur = (t & 1) ? buf1 : buf0;
    char* nxt = (t & 1) ? buf0 : buf1;

    // acc starts at m2[col]; BB = -2*bank, so acc ends at m2 - 2*<proj,bank>
    f32x4 acc[4][2];
#pragma unroll
    for (int Mt = 0; Mt < 4; ++Mt) {
#pragma unroll
      for (int q = 0; q < 4; ++q) { acc[Mt][0][q] = m2c0; acc[Mt][1][q] = m2c1; }
    }
    const char* b0 = cur + n0 * 512;
    const char* b1p = cur + (n0 + 16) * 512;

    bf16x8 bv[8];
    // ---- half 0: batch 8 ds_reads (ks 0..3), then 32 MFMA ----
#pragma unroll
    for (int ks = 0; ks < 4; ++ks) {
      bv[ks * 2 + 0] = *(const bf16x8*)(b0 + ((ks * 64 + lk * 16) ^ swz));
      bv[ks * 2 + 1] = *(const bf16x8*)(b1p + ((ks * 64 + lk * 16) ^ swz));
    }
    if (t < 127) {
#pragma unroll
      for (int i = 0; i < 4; ++i) {
        const int o = (w * 8 + i) * 1024 + lane * 16;
        const int n = o >> 9, b = o & 511;
        GLL((const char*)BB + ((size_t)(t + 1) * 128 + n) * 512 + (b ^ ((n & 7) << 4)),
            nxt + (w * 8 + i) * 1024);
      }
    }
    __builtin_amdgcn_s_setprio(1);
#pragma unroll
    for (int ks = 0; ks < 4; ++ks)
#pragma unroll
      for (int Nt = 0; Nt < 2; ++Nt)
#pragma unroll
        for (int Mt = 0; Mt < 4; ++Mt)
          acc[Mt][Nt] = MFMA(A[Mt][ks], bv[ks * 2 + Nt], acc[Mt][Nt]);
    __builtin_amdgcn_s_setprio(0);

    // ---- half 1: batch 8 ds_reads (ks 4..7), then 32 MFMA ----
#pragma unroll
    for (int ks = 0; ks < 4; ++ks) {
      bv[ks * 2 + 0] = *(const bf16x8*)(b0 + (((ks + 4) * 64 + lk * 16) ^ swz));
      bv[ks * 2 + 1] = *(const bf16x8*)(b1p + (((ks + 4) * 64 + lk * 16) ^ swz));
    }
    if (t < 127) {
#pragma unroll
      for (int i = 4; i < 8; ++i) {
        const int o = (w * 8 + i) * 1024 + lane * 16;
        const int n = o >> 9, b = o & 511;
        GLL((const char*)BB + ((size_t)(t + 1) * 128 + n) * 512 + (b ^ ((n & 7) << 4)),
            nxt + (w * 8 + i) * 1024);
      }
      m2c0 = m2[(t + 1) * 128 + n0];
      m2c1 = m2[(t + 1) * 128 + n0 + 16];
    }
    __builtin_amdgcn_s_setprio(1);
#pragma unroll
    for (int ks = 0; ks < 4; ++ks)
#pragma unroll
      for (int Nt = 0; Nt < 2; ++Nt)
#pragma unroll
        for (int Mt = 0; Mt < 4; ++Mt)
          acc[Mt][Nt] = MFMA(A[Mt][ks + 4], bv[ks * 2 + Nt], acc[Mt][Nt]);
    __builtin_amdgcn_s_setprio(0);

    // epilogue: fold into running min (pure fmin)
#pragma unroll
    for (int Mt = 0; Mt < 4; ++Mt)
#pragma unroll
      for (int q = 0; q < 4; ++q)
        minv[Mt][q] = fminf(minv[Mt][q], fminf(acc[Mt][0][q], acc[Mt][1][q]));
    __syncthreads();
  }

  // reduce min over the 16 col-lanes
#pragma unroll
  for (int Mt = 0; Mt < 4; ++Mt)
#pragma unroll
    for (int q = 0; q < 4; ++q) {
      float v = minv[Mt][q];
      v = fminf(v, __shfl_xor(v, 1)); v = fminf(v, __shfl_xor(v, 2));
      v = fminf(v, __shfl_xor(v, 4)); v = fminf(v, __shfl_xor(v, 8));
      minv[Mt][q] = v;
    }
  if (lr == 0) {
#pragma unroll
    for (int Mt = 0; Mt < 4; ++Mt)
#pragma unroll
      for (int q = 0; q < 4; ++q)
        minbuf[wn * 128 + wm * 64 + Mt * 16 + lk * 4 + q] = minv[Mt][q];
  }
  __syncthreads();
  if (tid < 128) {
    const float m = fminf(fminf(minbuf[tid], minbuf[128 + tid]),
                          fminf(minbuf[256 + tid], minbuf[384 + tid]));
    const float d2 = X2[r0 + tid] + m;
    out[r0 + tid] = sqrtf(fmaxf(d2, 0.f));
  }
}

extern "C" void kernel_launch(void* const* d_in, const int* in_sizes, int n_in,
                              void* d_out, int out_size, void* d_ws, size_t ws_size,
                              hipStream_t stream) {
  const float* F = (const float*)d_in[0];
  const float* W1 = (const float*)d_in[1];
  const float* b1 = (const float*)d_in[2];
  const float* W2 = (const float*)d_in[3];
  const float* b2 = (const float*)d_in[4];
  const float* bank = (const float*)d_in[5];
  float* out = (float*)d_out;

  char* ws = (char*)d_ws;
  bf16* BB = (bf16*)(ws + 0);            //  8,388,608 B   (-2 * bank, bf16)
  float* m2 = (float*)(ws + 8388608);    //     65,536 B
  bf16* W1t = (bf16*)(ws + 8454144);     //  1,048,576 B
  bf16* W2t = (bf16*)(ws + 9502720);     //    262,144 B
  bf16* H = (bf16*)(ws + 9764864);       // 33,554,432 B
  bf16* PROJ = (bf16*)(ws + 43319296);   // 16,777,216 B
  float* X2 = (float*)(ws + 60096512);   //    131,072 B  -> total 60,227,584 B

  prep_w<<<2560, 256, 0, stream>>>(W1, W2, W1t, W2t);
  prep_bank<<<4096, 256, 0, stream>>>(bank, BB, m2);
  mlp1_kernel<<<256, 512, 0, stream>>>(F, W1t, b1, H);
  mlp2_kernel<<<256, 512, 0, stream>>>(H, W2t, b2, PROJ, X2);
  dist_kernel<<<256, 512, 0, stream>>>(PROJ, BB, m2, X2, out);
}

// Round 5
// 275.545 us; speedup vs baseline: 1.2605x; 1.0806x over previous
//
#include <hip/hip_runtime.h>
#include <math.h>

typedef __bf16 bf16;
typedef __attribute__((ext_vector_type(8))) __bf16 bf16x8;
typedef __attribute__((ext_vector_type(4))) float f32x4;
typedef __attribute__((ext_vector_type(2))) unsigned long ulongx2;

typedef __attribute__((address_space(1))) const void gvoid;
typedef __attribute__((address_space(3))) void lvoid;
#define GLL(g, l) __builtin_amdgcn_global_load_lds((gvoid*)(g), (lvoid*)(l), 16, 0, 0)
#define MFMA(a, b, c) __builtin_amdgcn_mfma_f32_16x16x32_bf16((a), (b), (c), 0, 0, 0)
#define MFMA8(a, b, c) __builtin_amdgcn_mfma_f32_16x16x32_fp8_fp8((long)(a), (long)(b), (c), 0, 0, 0)

__device__ __forceinline__ int swz128(int row, int kb) { return kb ^ ((row & 7) << 4); }

// ---- fp8 e4m3fn encode/decode (OCP: bias 7, max 448, no inf) ----
__device__ __forceinline__ unsigned char f32_to_e4m3(float x) {
  const unsigned s = (__float_as_uint(x) >> 24) & 0x80;
  float ax = fminf(fabsf(x), 448.f);
  unsigned e;
  if (ax >= 0.015625f) {  // normal range (>= 2^-6)
    const unsigned u = __float_as_uint(ax);
    const unsigned t = u + 0x7FFFF + ((u >> 20) & 1);  // RNE to 3 mantissa bits
    e = (((t >> 23) - 120) << 3) | ((t >> 20) & 7);
  } else {  // subnormal: value = q * 2^-9, q in 0..8 (8 == 2^-6 normal, continuous)
    e = (unsigned)__float2int_rn(ax * 512.f);
  }
  return (unsigned char)(s | e);
}
__device__ __forceinline__ float e4m3_to_f32(unsigned char b) {
  const unsigned s = ((unsigned)b & 0x80) << 24;
  const unsigned em = b & 0x7F;
  float v;
  if (em >= 8) v = __uint_as_float((((em >> 3) + 120) << 23) | ((em & 7) << 20));
  else v = (float)em * 0.001953125f;
  return __uint_as_float(__float_as_uint(v) | s);
}

// ---------------- prep: W1 [1024][512] -> W1t bf16 [512][1024]; W2 [512][256] -> W2t [256][512]
__global__ __launch_bounds__(256) void prep_w(const float* __restrict__ W1,
                                              const float* __restrict__ W2,
                                              bf16* __restrict__ W1t, bf16* __restrict__ W2t) {
  const int t = blockIdx.x * 256 + threadIdx.x;
  if (t < 512 * 1024) {
    const int h = t & 511, k = t >> 9;
    W1t[h * 1024 + k] = (bf16)W1[k * 512 + h];
  } else {
    const int u = t - 512 * 1024;
    const int e = u & 255, k = u >> 8;
    W2t[e * 512 + k] = (bf16)W2[k * 256 + e];
  }
}

// ---------------- prep: bank fp32 [16384][256] -> BB8 = e4m3(-2*bank), permuted+swizzled
// global byte layout per row: pos(k) = (lk*64 + ks*8 + j) ^ ((row&3)<<4), k = ks*32+lk*8+j.
// m2[row] = sum of (decoded/-2)^2 (consistent with the quantized values used in MFMA).
__global__ __launch_bounds__(256) void prep_bank(const float* __restrict__ bank,
                                                 unsigned char* __restrict__ BB8,
                                                 float* __restrict__ m2) {
  const int tid = threadIdx.x, lane = tid & 63, w = tid >> 6;
  const int row = blockIdx.x * 4 + w;
  const float4 v = *reinterpret_cast<const float4*>(bank + (size_t)row * 256 + lane * 4);
  uchar4 q;
  float ssum = 0.f;
  {
    const float xs[4] = {v.x, v.y, v.z, v.w};
    unsigned char qb[4];
#pragma unroll
    for (int e = 0; e < 4; ++e) {
      qb[e] = f32_to_e4m3(-2.f * xs[e]);
      const float d = e4m3_to_f32(qb[e]);
      ssum += d * d;
    }
    q.x = qb[0]; q.y = qb[1]; q.z = qb[2]; q.w = qb[3];
  }
#pragma unroll
  for (int off = 1; off < 64; off <<= 1) ssum += __shfl_xor(ssum, off);
  const int k0 = lane * 4;
  const int ks = k0 >> 5, lk = (k0 >> 3) & 3, j0 = k0 & 7;
  const int pos = (lk * 64 + ks * 8 + j0) ^ ((row & 3) << 4);
  *reinterpret_cast<uchar4*>(BB8 + (size_t)row * 256 + pos) = q;
  if (lane == 0) m2[row] = ssum * 0.25f;  // (d/2)^2 summed
}

// ---------------- mlp1: H[32768][512] = relu(F @ W1 + b1), bf16 out
__global__ __launch_bounds__(512, 2) void mlp1_kernel(const float* __restrict__ F,
                                                      const bf16* __restrict__ W1t,
                                                      const float* __restrict__ b1,
                                                      bf16* __restrict__ H) {
  __shared__ __align__(16) char smem[81920];
  char* sA = smem;          // F chunk bf16 [128 rows][128B], swizzled
  char* sB = smem + 16384;  // W1t chunk [512 n][128B], swizzled

  const int tid = threadIdx.x;
  const int w = tid >> 6, lane = tid & 63;
  const int wm = w >> 2, wn = w & 3;
  const int lr = lane & 15, lk = lane >> 4;
  const size_t r0 = (size_t)blockIdx.x * 128;

  f32x4 acc[4][8];
  const f32x4 z = {0.f, 0.f, 0.f, 0.f};
#pragma unroll
  for (int m = 0; m < 4; ++m)
#pragma unroll
    for (int n = 0; n < 8; ++n) acc[m][n] = z;

  for (int kc = 0; kc < 16; ++kc) {
    {
      const int fr = tid >> 2, kg = (tid & 3) << 4;
      const float* fsrc = F + (r0 + fr) * 1024 + kc * 64 + kg;
      const float4 f0 = *reinterpret_cast<const float4*>(fsrc);
      const float4 f1 = *reinterpret_cast<const float4*>(fsrc + 4);
      const float4 f2 = *reinterpret_cast<const float4*>(fsrc + 8);
      const float4 f3 = *reinterpret_cast<const float4*>(fsrc + 12);
      bf16x8 p0, p1;
      p0[0] = (bf16)f0.x; p0[1] = (bf16)f0.y; p0[2] = (bf16)f0.z; p0[3] = (bf16)f0.w;
      p0[4] = (bf16)f1.x; p0[5] = (bf16)f1.y; p0[6] = (bf16)f1.z; p0[7] = (bf16)f1.w;
      p1[0] = (bf16)f2.x; p1[1] = (bf16)f2.y; p1[2] = (bf16)f2.z; p1[3] = (bf16)f2.w;
      p1[4] = (bf16)f3.x; p1[5] = (bf16)f3.y; p1[6] = (bf16)f3.z; p1[7] = (bf16)f3.w;
      const int bb = kg * 2;
      *(bf16x8*)(sA + fr * 128 + swz128(fr, bb)) = p0;
      *(bf16x8*)(sA + fr * 128 + swz128(fr, bb + 16)) = p1;
    }
#pragma unroll
    for (int i = 0; i < 8; ++i) {
      const int o = (w * 8 + i) * 1024 + lane * 16;
      const int n = o >> 7, b = o & 127;
      GLL((const char*)W1t + n * 2048 + kc * 128 + swz128(n, b), sB + (w * 8 + i) * 1024);
    }
    __syncthreads();
#pragma unroll
    for (int ks = 0; ks < 2; ++ks) {
      bf16x8 av[4];
#pragma unroll
      for (int Mt = 0; Mt < 4; ++Mt) {
        const int row = wm * 64 + Mt * 16 + lr;
        av[Mt] = *(const bf16x8*)(sA + row * 128 + swz128(row, ks * 64 + lk * 16));
      }
#pragma unroll
      for (int Nt = 0; Nt < 8; ++Nt) {
        const int n = wn * 128 + Nt * 16 + lr;
        const bf16x8 bv = *(const bf16x8*)(sB + n * 128 + swz128(n, ks * 64 + lk * 16));
#pragma unroll
        for (int Mt = 0; Mt < 4; ++Mt) acc[Mt][Nt] = MFMA(av[Mt], bv, acc[Mt][Nt]);
      }
    }
    __syncthreads();
  }
#pragma unroll
  for (int Nt = 0; Nt < 8; ++Nt) {
    const int col = wn * 128 + Nt * 16 + lr;
    const float bias = b1[col];
#pragma unroll
    for (int Mt = 0; Mt < 4; ++Mt) {
      const size_t rowb = r0 + wm * 64 + Mt * 16 + lk * 4;
#pragma unroll
      for (int q = 0; q < 4; ++q)
        H[(rowb + q) * 512 + col] = (bf16)fmaxf(acc[Mt][Nt][q] + bias, 0.f);
    }
  }
}

// ---------------- mlp2: PROJ8[32768][256] fp8 = e4m3(H @ W2 + b2); X2 from decoded fp8
__global__ __launch_bounds__(512, 2) void mlp2_kernel(const bf16* __restrict__ H,
                                                      const bf16* __restrict__ W2t,
                                                      const float* __restrict__ b2,
                                                      unsigned char* __restrict__ PROJ8,
                                                      float* __restrict__ X2) {
  __shared__ __align__(16) char smem[51200];
  char* sA = smem;                        // H chunk [128][128B] swizzled
  char* sB = smem + 16384;                // W2t chunk [256][128B] swizzled
  float* sX2 = (float*)(smem + 49152);    // [4][128]

  const int tid = threadIdx.x;
  const int w = tid >> 6, lane = tid & 63;
  const int wm = w >> 2, wn = w & 3;
  const int lr = lane & 15, lk = lane >> 4;
  const size_t r0 = (size_t)blockIdx.x * 128;

  f32x4 acc[4][4];
  const f32x4 z = {0.f, 0.f, 0.f, 0.f};
#pragma unroll
  for (int m = 0; m < 4; ++m)
#pragma unroll
    for (int n = 0; n < 4; ++n) acc[m][n] = z;

  for (int kc = 0; kc < 8; ++kc) {
#pragma unroll
    for (int i = 0; i < 2; ++i) {
      const int o = (w * 2 + i) * 1024 + lane * 16;
      const int row = o >> 7, b = o & 127;
      GLL((const char*)H + (r0 + row) * 1024 + kc * 128 + swz128(row, b), sA + (w * 2 + i) * 1024);
    }
#pragma unroll
    for (int i = 0; i < 4; ++i) {
      const int o = (w * 4 + i) * 1024 + lane * 16;
      const int n = o >> 7, b = o & 127;
      GLL((const char*)W2t + n * 1024 + kc * 128 + swz128(n, b), sB + (w * 4 + i) * 1024);
    }
    __syncthreads();
#pragma unroll
    for (int ks = 0; ks < 2; ++ks) {
      bf16x8 av[4];
#pragma unroll
      for (int Mt = 0; Mt < 4; ++Mt) {
        const int row = wm * 64 + Mt * 16 + lr;
        av[Mt] = *(const bf16x8*)(sA + row * 128 + swz128(row, ks * 64 + lk * 16));
      }
#pragma unroll
      for (int Nt = 0; Nt < 4; ++Nt) {
        const int n = wn * 64 + Nt * 16 + lr;
        const bf16x8 bv = *(const bf16x8*)(sB + n * 128 + swz128(n, ks * 64 + lk * 16));
#pragma unroll
        for (int Mt = 0; Mt < 4; ++Mt) acc[Mt][Nt] = MFMA(av[Mt], bv, acc[Mt][Nt]);
      }
    }
    __syncthreads();
  }
  // epilogue: +b2, quantize to fp8, store PROJ8, accumulate consistent x2
  float x2p[4][4];
#pragma unroll
  for (int m = 0; m < 4; ++m)
#pragma unroll
    for (int q = 0; q < 4; ++q) x2p[m][q] = 0.f;
#pragma unroll
  for (int Nt = 0; Nt < 4; ++Nt) {
    const int col = wn * 64 + Nt * 16 + lr;
    const float bias = b2[col];
#pragma unroll
    for (int Mt = 0; Mt < 4; ++Mt) {
      const size_t rowb = r0 + wm * 64 + Mt * 16 + lk * 4;
#pragma unroll
      for (int q = 0; q < 4; ++q) {
        const float p = acc[Mt][Nt][q] + bias;
        const unsigned char qb = f32_to_e4m3(p);
        PROJ8[(rowb + q) * 256 + col] = qb;
        const float d = e4m3_to_f32(qb);
        x2p[Mt][q] += d * d;
      }
    }
  }
#pragma unroll
  for (int Mt = 0; Mt < 4; ++Mt)
#pragma unroll
    for (int q = 0; q < 4; ++q) {
      float v = x2p[Mt][q];
      v += __shfl_xor(v, 1); v += __shfl_xor(v, 2);
      v += __shfl_xor(v, 4); v += __shfl_xor(v, 8);
      x2p[Mt][q] = v;
    }
  __syncthreads();
  if (lr == 0) {
#pragma unroll
    for (int Mt = 0; Mt < 4; ++Mt)
#pragma unroll
      for (int q = 0; q < 4; ++q)
        sX2[wn * 128 + wm * 64 + Mt * 16 + lk * 4 + q] = x2p[Mt][q];
  }
  __syncthreads();
  if (tid < 128)
    X2[r0 + tid] = sX2[tid] + sX2[128 + tid] + sX2[256 + tid] + sX2[384 + tid];
}

// ---------------- dist (fp8): out[r] = sqrt(max(x2[r] + min_m(m2[m] - 2*proj.bank), 0))
// {1,8} decomposition: each wave = 128 rows x 16 banks. A (fp8 proj) in regs (128 VGPR).
// BB8 = -2*bank fp8, permuted so one b128 = two K-fragments; acc init = m2[col].
__global__ __launch_bounds__(512, 2) void dist_kernel(const unsigned char* __restrict__ PROJ8,
                                                      const unsigned char* __restrict__ BB8,
                                                      const float* __restrict__ m2,
                                                      const float* __restrict__ X2,
                                                      float* __restrict__ out) {
  __shared__ __align__(16) char smem[69632];
  char* buf0 = smem;                        // 32 KiB: 128 banks x 256B (permuted+swizzled)
  char* buf1 = smem + 32768;
  float* minbuf = (float*)(smem + 65536);   // [8][128]

  const int tid = threadIdx.x;
  const int w = tid >> 6, lane = tid & 63;
  const int lr = lane & 15, lk = lane >> 4;
  const size_t r0 = (size_t)blockIdx.x * 128;

  // A fragments: A[Mt][ks] = 8 fp8 of row (r0+Mt*16+lr), k = ks*32 + lk*8 .. +8
  unsigned long A[8][8];
#pragma unroll
  for (int Mt = 0; Mt < 8; ++Mt)
#pragma unroll
    for (int ks = 0; ks < 8; ++ks)
      A[Mt][ks] = *(const unsigned long*)(PROJ8 + (r0 + Mt * 16 + lr) * 256 + ks * 32 + lk * 8);

  // stage tile 0
#pragma unroll
  for (int i = 0; i < 4; ++i)
    GLL(BB8 + (size_t)((w * 4 + i) * 4 + lk) * 256 + lr * 16, buf0 + (w * 4 + i) * 1024);

  const int n0 = w * 16 + lr;         // this lane's bank row within the tile (= C col)
  const int rswz = (lr & 3) << 4;
  float m2c = m2[n0];

  f32x4 minv[8];
#pragma unroll
  for (int Mt = 0; Mt < 8; ++Mt)
#pragma unroll
    for (int q = 0; q < 4; ++q) minv[Mt][q] = 3.0e38f;

  __syncthreads();

  for (int t = 0; t < 128; ++t) {
    char* cur = (t & 1) ? buf1 : buf0;
    char* nxt = (t & 1) ? buf0 : buf1;

    // 4 x ds_read_b128: each = fragments (2*ksp, 2*ksp+1) for this lane's bank column
    ulongx2 bv[4];
#pragma unroll
    for (int ksp = 0; ksp < 4; ++ksp)
      bv[ksp] = *(const ulongx2*)(cur + n0 * 256 + ((lk * 64 + ksp * 16) ^ rswz));

    float m2n = 0.f;
    if (t < 127) {
#pragma unroll
      for (int i = 0; i < 4; ++i)
        GLL(BB8 + ((size_t)(t + 1) * 128 + (w * 4 + i) * 4 + lk) * 256 + lr * 16,
            nxt + (w * 4 + i) * 1024);
      m2n = m2[(t + 1) * 128 + n0];
    }

    f32x4 acc[8];
#pragma unroll
    for (int Mt = 0; Mt < 8; ++Mt)
#pragma unroll
      for (int q = 0; q < 4; ++q) acc[Mt][q] = m2c;

    __builtin_amdgcn_s_setprio(1);
#pragma unroll
    for (int ksp = 0; ksp < 4; ++ksp) {
#pragma unroll
      for (int Mt = 0; Mt < 8; ++Mt) acc[Mt] = MFMA8(A[Mt][2 * ksp], bv[ksp].x, acc[Mt]);
#pragma unroll
      for (int Mt = 0; Mt < 8; ++Mt) acc[Mt] = MFMA8(A[Mt][2 * ksp + 1], bv[ksp].y, acc[Mt]);
    }
    __builtin_amdgcn_s_setprio(0);

#pragma unroll
    for (int Mt = 0; Mt < 8; ++Mt)
#pragma unroll
      for (int q = 0; q < 4; ++q) minv[Mt][q] = fminf(minv[Mt][q], acc[Mt][q]);

    m2c = m2n;
    __syncthreads();
  }

  // reduce min over the 16 bank-column lanes (lr); rows live at lk*4+q
#pragma unroll
  for (int Mt = 0; Mt < 8; ++Mt)
#pragma unroll
    for (int q = 0; q < 4; ++q) {
      float v = minv[Mt][q];
      v = fminf(v, __shfl_xor(v, 1)); v = fminf(v, __shfl_xor(v, 2));
      v = fminf(v, __shfl_xor(v, 4)); v = fminf(v, __shfl_xor(v, 8));
      minv[Mt][q] = v;
    }
  if (lr == 0) {
#pragma unroll
    for (int Mt = 0; Mt < 8; ++Mt)
#pragma unroll
      for (int q = 0; q < 4; ++q)
        minbuf[w * 128 + Mt * 16 + lk * 4 + q] = minv[Mt][q];
  }
  __syncthreads();
  if (tid < 128) {
    float m = minbuf[tid];
#pragma unroll
    for (int v = 1; v < 8; ++v) m = fminf(m, minbuf[v * 128 + tid]);
    const float d2 = X2[r0 + tid] + m;
    out[r0 + tid] = sqrtf(fmaxf(d2, 0.f));
  }
}

extern "C" void kernel_launch(void* const* d_in, const int* in_sizes, int n_in,
                              void* d_out, int out_size, void* d_ws, size_t ws_size,
                              hipStream_t stream) {
  const float* F = (const float*)d_in[0];
  const float* W1 = (const float*)d_in[1];
  const float* b1 = (const float*)d_in[2];
  const float* W2 = (const float*)d_in[3];
  const float* b2 = (const float*)d_in[4];
  const float* bank = (const float*)d_in[5];
  float* out = (float*)d_out;

  char* ws = (char*)d_ws;
  unsigned char* BB8 = (unsigned char*)(ws + 0);   //  4,194,304 B (e4m3(-2*bank), permuted)
  float* m2 = (float*)(ws + 4194304);              //     65,536 B
  bf16* W1t = (bf16*)(ws + 4259840);               //  1,048,576 B
  bf16* W2t = (bf16*)(ws + 5308416);               //    262,144 B
  bf16* H = (bf16*)(ws + 5570560);                 // 33,554,432 B
  unsigned char* PROJ8 = (unsigned char*)(ws + 39124992);  // 8,388,608 B
  float* X2 = (float*)(ws + 47513600);             //    131,072 B -> total 47,644,672 B

  prep_w<<<2560, 256, 0, stream>>>(W1, W2, W1t, W2t);
  prep_bank<<<4096, 256, 0, stream>>>(bank, BB8, m2);
  mlp1_kernel<<<256, 512, 0, stream>>>(F, W1t, b1, H);
  mlp2_kernel<<<256, 512, 0, stream>>>(H, W2t, b2, PROJ8, X2);
  dist_kernel<<<256, 512, 0, stream>>>(PROJ8, BB8, m2, X2, out);
}

// Round 6
// 259.967 us; speedup vs baseline: 1.3360x; 1.0599x over previous
//
#include <hip/hip_runtime.h>
#include <math.h>

typedef __bf16 bf16;
typedef __attribute__((ext_vector_type(8))) __bf16 bf16x8;
typedef __attribute__((ext_vector_type(4))) float f32x4;
typedef __attribute__((ext_vector_type(2))) unsigned long ulongx2;

typedef __attribute__((address_space(1))) const void gvoid;
typedef __attribute__((address_space(3))) void lvoid;
#define GLL(g, l) __builtin_amdgcn_global_load_lds((gvoid*)(g), (lvoid*)(l), 16, 0, 0)
#define GLL4(g, l) __builtin_amdgcn_global_load_lds((gvoid*)(g), (lvoid*)(l), 4, 0, 0)
#define MFMA(a, b, c) __builtin_amdgcn_mfma_f32_16x16x32_bf16((a), (b), (c), 0, 0, 0)
#define MFMA8(a, b, c) __builtin_amdgcn_mfma_f32_16x16x32_fp8_fp8((long)(a), (long)(b), (c), 0, 0, 0)

__device__ __forceinline__ int swz128(int row, int kb) { return kb ^ ((row & 7) << 4); }

// ---- fp8 e4m3fn encode/decode (OCP: bias 7, max 448, no inf) ----
__device__ __forceinline__ unsigned char f32_to_e4m3(float x) {
  const unsigned s = (__float_as_uint(x) >> 24) & 0x80;
  float ax = fminf(fabsf(x), 448.f);
  unsigned e;
  if (ax >= 0.015625f) {  // normal range (>= 2^-6)
    const unsigned u = __float_as_uint(ax);
    const unsigned t = u + 0x7FFFF + ((u >> 20) & 1);  // RNE to 3 mantissa bits
    e = (((t >> 23) - 120) << 3) | ((t >> 20) & 7);
  } else {  // subnormal: value = q * 2^-9, q in 0..8
    e = (unsigned)__float2int_rn(ax * 512.f);
  }
  return (unsigned char)(s | e);
}
__device__ __forceinline__ float e4m3_to_f32(unsigned char b) {
  const unsigned s = ((unsigned)b & 0x80) << 24;
  const unsigned em = b & 0x7F;
  float v;
  if (em >= 8) v = __uint_as_float((((em >> 3) + 120) << 23) | ((em & 7) << 20));
  else v = (float)em * 0.001953125f;
  return __uint_as_float(__float_as_uint(v) | s);
}

// ---------------- prep: W1 [1024][512] -> W1t bf16 [512][1024]; W2 [512][256] -> W2t [256][512]
__global__ __launch_bounds__(256) void prep_w(const float* __restrict__ W1,
                                              const float* __restrict__ W2,
                                              bf16* __restrict__ W1t, bf16* __restrict__ W2t) {
  const int t = blockIdx.x * 256 + threadIdx.x;
  if (t < 512 * 1024) {
    const int h = t & 511, k = t >> 9;
    W1t[h * 1024 + k] = (bf16)W1[k * 512 + h];
  } else {
    const int u = t - 512 * 1024;
    const int e = u & 255, k = u >> 8;
    W2t[e * 512 + k] = (bf16)W2[k * 256 + e];
  }
}

// ---------------- prep: bank fp32 [16384][256] -> BB8 = e4m3(-2*bank), permuted+swizzled
// byte layout per row: pos(k) = (lk*64 + ks*8 + j) ^ ((row&7)<<4), k = ks*32+lk*8+j.
// m2[row] consistent with the quantized values used in MFMA.
__global__ __launch_bounds__(256) void prep_bank(const float* __restrict__ bank,
                                                 unsigned char* __restrict__ BB8,
                                                 float* __restrict__ m2) {
  const int tid = threadIdx.x, lane = tid & 63, w = tid >> 6;
  const int row = blockIdx.x * 4 + w;
  const float4 v = *reinterpret_cast<const float4*>(bank + (size_t)row * 256 + lane * 4);
  uchar4 q;
  float ssum = 0.f;
  {
    const float xs[4] = {v.x, v.y, v.z, v.w};
    unsigned char qb[4];
#pragma unroll
    for (int e = 0; e < 4; ++e) {
      qb[e] = f32_to_e4m3(-2.f * xs[e]);
      const float d = e4m3_to_f32(qb[e]);
      ssum += d * d;
    }
    q.x = qb[0]; q.y = qb[1]; q.z = qb[2]; q.w = qb[3];
  }
#pragma unroll
  for (int off = 1; off < 64; off <<= 1) ssum += __shfl_xor(ssum, off);
  const int k0 = lane * 4;
  const int ks = k0 >> 5, lk = (k0 >> 3) & 3, j0 = k0 & 7;
  const int pos = (lk * 64 + ks * 8 + j0) ^ ((row & 7) << 4);
  *reinterpret_cast<uchar4*>(BB8 + (size_t)row * 256 + pos) = q;
  if (lane == 0) m2[row] = ssum * 0.25f;  // (d/2)^2 summed
}

// ---------------- mlp1: H[32768][512] = relu(F @ W1 + b1), bf16 out
__global__ __launch_bounds__(512, 2) void mlp1_kernel(const float* __restrict__ F,
                                                      const bf16* __restrict__ W1t,
                                                      const float* __restrict__ b1,
                                                      bf16* __restrict__ H) {
  __shared__ __align__(16) char smem[81920];
  char* sA = smem;          // F chunk bf16 [128 rows][128B], swizzled
  char* sB = smem + 16384;  // W1t chunk [512 n][128B], swizzled

  const int tid = threadIdx.x;
  const int w = tid >> 6, lane = tid & 63;
  const int wm = w >> 2, wn = w & 3;
  const int lr = lane & 15, lk = lane >> 4;
  const size_t r0 = (size_t)blockIdx.x * 128;

  f32x4 acc[4][8];
  const f32x4 z = {0.f, 0.f, 0.f, 0.f};
#pragma unroll
  for (int m = 0; m < 4; ++m)
#pragma unroll
    for (int n = 0; n < 8; ++n) acc[m][n] = z;

  for (int kc = 0; kc < 16; ++kc) {
    {
      const int fr = tid >> 2, kg = (tid & 3) << 4;
      const float* fsrc = F + (r0 + fr) * 1024 + kc * 64 + kg;
      const float4 f0 = *reinterpret_cast<const float4*>(fsrc);
      const float4 f1 = *reinterpret_cast<const float4*>(fsrc + 4);
      const float4 f2 = *reinterpret_cast<const float4*>(fsrc + 8);
      const float4 f3 = *reinterpret_cast<const float4*>(fsrc + 12);
      bf16x8 p0, p1;
      p0[0] = (bf16)f0.x; p0[1] = (bf16)f0.y; p0[2] = (bf16)f0.z; p0[3] = (bf16)f0.w;
      p0[4] = (bf16)f1.x; p0[5] = (bf16)f1.y; p0[6] = (bf16)f1.z; p0[7] = (bf16)f1.w;
      p1[0] = (bf16)f2.x; p1[1] = (bf16)f2.y; p1[2] = (bf16)f2.z; p1[3] = (bf16)f2.w;
      p1[4] = (bf16)f3.x; p1[5] = (bf16)f3.y; p1[6] = (bf16)f3.z; p1[7] = (bf16)f3.w;
      const int bb = kg * 2;
      *(bf16x8*)(sA + fr * 128 + swz128(fr, bb)) = p0;
      *(bf16x8*)(sA + fr * 128 + swz128(fr, bb + 16)) = p1;
    }
#pragma unroll
    for (int i = 0; i < 8; ++i) {
      const int o = (w * 8 + i) * 1024 + lane * 16;
      const int n = o >> 7, b = o & 127;
      GLL((const char*)W1t + n * 2048 + kc * 128 + swz128(n, b), sB + (w * 8 + i) * 1024);
    }
    __syncthreads();
#pragma unroll
    for (int ks = 0; ks < 2; ++ks) {
      bf16x8 av[4];
#pragma unroll
      for (int Mt = 0; Mt < 4; ++Mt) {
        const int row = wm * 64 + Mt * 16 + lr;
        av[Mt] = *(const bf16x8*)(sA + row * 128 + swz128(row, ks * 64 + lk * 16));
      }
#pragma unroll
      for (int Nt = 0; Nt < 8; ++Nt) {
        const int n = wn * 128 + Nt * 16 + lr;
        const bf16x8 bv = *(const bf16x8*)(sB + n * 128 + swz128(n, ks * 64 + lk * 16));
#pragma unroll
        for (int Mt = 0; Mt < 4; ++Mt) acc[Mt][Nt] = MFMA(av[Mt], bv, acc[Mt][Nt]);
      }
    }
    __syncthreads();
  }
#pragma unroll
  for (int Nt = 0; Nt < 8; ++Nt) {
    const int col = wn * 128 + Nt * 16 + lr;
    const float bias = b1[col];
#pragma unroll
    for (int Mt = 0; Mt < 4; ++Mt) {
      const size_t rowb = r0 + wm * 64 + Mt * 16 + lk * 4;
#pragma unroll
      for (int q = 0; q < 4; ++q)
        H[(rowb + q) * 512 + col] = (bf16)fmaxf(acc[Mt][Nt][q] + bias, 0.f);
    }
  }
}

// ---------------- mlp2: PROJ8[32768][256] fp8 = e4m3(H @ W2 + b2); X2 from decoded fp8
__global__ __launch_bounds__(512, 2) void mlp2_kernel(const bf16* __restrict__ H,
                                                      const bf16* __restrict__ W2t,
                                                      const float* __restrict__ b2,
                                                      unsigned char* __restrict__ PROJ8,
                                                      float* __restrict__ X2) {
  __shared__ __align__(16) char smem[51200];
  char* sA = smem;                        // H chunk [128][128B] swizzled
  char* sB = smem + 16384;                // W2t chunk [256][128B] swizzled
  float* sX2 = (float*)(smem + 49152);    // [4][128]

  const int tid = threadIdx.x;
  const int w = tid >> 6, lane = tid & 63;
  const int wm = w >> 2, wn = w & 3;
  const int lr = lane & 15, lk = lane >> 4;
  const size_t r0 = (size_t)blockIdx.x * 128;

  f32x4 acc[4][4];
  const f32x4 z = {0.f, 0.f, 0.f, 0.f};
#pragma unroll
  for (int m = 0; m < 4; ++m)
#pragma unroll
    for (int n = 0; n < 4; ++n) acc[m][n] = z;

  for (int kc = 0; kc < 8; ++kc) {
#pragma unroll
    for (int i = 0; i < 2; ++i) {
      const int o = (w * 2 + i) * 1024 + lane * 16;
      const int row = o >> 7, b = o & 127;
      GLL((const char*)H + (r0 + row) * 1024 + kc * 128 + swz128(row, b), sA + (w * 2 + i) * 1024);
    }
#pragma unroll
    for (int i = 0; i < 4; ++i) {
      const int o = (w * 4 + i) * 1024 + lane * 16;
      const int n = o >> 7, b = o & 127;
      GLL((const char*)W2t + n * 1024 + kc * 128 + swz128(n, b), sB + (w * 4 + i) * 1024);
    }
    __syncthreads();
#pragma unroll
    for (int ks = 0; ks < 2; ++ks) {
      bf16x8 av[4];
#pragma unroll
      for (int Mt = 0; Mt < 4; ++Mt) {
        const int row = wm * 64 + Mt * 16 + lr;
        av[Mt] = *(const bf16x8*)(sA + row * 128 + swz128(row, ks * 64 + lk * 16));
      }
#pragma unroll
      for (int Nt = 0; Nt < 4; ++Nt) {
        const int n = wn * 64 + Nt * 16 + lr;
        const bf16x8 bv = *(const bf16x8*)(sB + n * 128 + swz128(n, ks * 64 + lk * 16));
#pragma unroll
        for (int Mt = 0; Mt < 4; ++Mt) acc[Mt][Nt] = MFMA(av[Mt], bv, acc[Mt][Nt]);
      }
    }
    __syncthreads();
  }
  // epilogue: +b2, quantize to fp8, store PROJ8, accumulate consistent x2
  float x2p[4][4];
#pragma unroll
  for (int m = 0; m < 4; ++m)
#pragma unroll
    for (int q = 0; q < 4; ++q) x2p[m][q] = 0.f;
#pragma unroll
  for (int Nt = 0; Nt < 4; ++Nt) {
    const int col = wn * 64 + Nt * 16 + lr;
    const float bias = b2[col];
#pragma unroll
    for (int Mt = 0; Mt < 4; ++Mt) {
      const size_t rowb = r0 + wm * 64 + Mt * 16 + lk * 4;
#pragma unroll
      for (int q = 0; q < 4; ++q) {
        const float p = acc[Mt][Nt][q] + bias;
        const unsigned char qb = f32_to_e4m3(p);
        PROJ8[(rowb + q) * 256 + col] = qb;
        const float d = e4m3_to_f32(qb);
        x2p[Mt][q] += d * d;
      }
    }
  }
#pragma unroll
  for (int Mt = 0; Mt < 4; ++Mt)
#pragma unroll
    for (int q = 0; q < 4; ++q) {
      float v = x2p[Mt][q];
      v += __shfl_xor(v, 1); v += __shfl_xor(v, 2);
      v += __shfl_xor(v, 4); v += __shfl_xor(v, 8);
      x2p[Mt][q] = v;
    }
  __syncthreads();
  if (lr == 0) {
#pragma unroll
    for (int Mt = 0; Mt < 4; ++Mt)
#pragma unroll
      for (int q = 0; q < 4; ++q)
        sX2[wn * 128 + wm * 64 + Mt * 16 + lk * 4 + q] = x2p[Mt][q];
  }
  __syncthreads();
  if (tid < 128)
    X2[r0 + tid] = sX2[tid] + sX2[128 + tid] + sX2[256 + tid] + sX2[384 + tid];
}

// ---------------- dist (fp8, barrier-free): each wave's LDS segments are private, so the
// main loop has NO __syncthreads. 4-buffer ring, depth-3 prefetch, counted vmcnt(10)
// (5 VMEM ops/tile/wave: 4 data GLL + 1 m2 GLL). Arrays padded by 3 dummy tiles.
__global__ __launch_bounds__(512, 2) void dist_kernel(const unsigned char* __restrict__ PROJ8,
                                                      const unsigned char* __restrict__ BB8,
                                                      const float* __restrict__ m2g,
                                                      const float* __restrict__ X2,
                                                      float* __restrict__ out) {
  __shared__ __align__(16) char smem[143360];
  // [0, 131072)        : 4 data buffers x 32 KiB (wave w owns bytes w*4096..+4096 of each)
  // [131072, 139264)   : 4 m2 buffers x 2 KiB (wave w owns bytes w*256..+256 of each)
  // [139264, 143360)   : minbuf float[8][128]
  float* minbuf = (float*)(smem + 139264);

  const int tid = threadIdx.x;
  const int w = tid >> 6, lane = tid & 63;
  const int lr = lane & 15, lk = lane >> 4;
  const size_t r0 = (size_t)blockIdx.x * 128;

  // A fragments: A[Mt][ks] = 8 fp8 of row (r0+Mt*16+lr), k = ks*32 + lk*8 .. +8
  unsigned long A[8][8];
#pragma unroll
  for (int Mt = 0; Mt < 8; ++Mt)
#pragma unroll
    for (int ks = 0; ks < 8; ++ks)
      A[Mt][ks] = *(const unsigned long*)(PROJ8 + (r0 + Mt * 16 + lr) * 256 + ks * 32 + lk * 8);

  const int n0 = w * 16 + lr;         // this lane's bank row within the tile (= C col)
  const int rswz = (lr & 7) << 4;

  // prologue: stage tiles 0,1,2 (5 VMEM ops each)
#pragma unroll
  for (int p = 0; p < 3; ++p) {
    char* db = smem + (p & 3) * 32768 + w * 4096;
#pragma unroll
    for (int i = 0; i < 4; ++i)
      GLL(BB8 + ((size_t)p * 128 + (w * 4 + i) * 4 + lk) * 256 + lr * 16, db + i * 1024);
    GLL4(m2g + p * 128 + w * 16 + lr, smem + 131072 + (p & 3) * 2048 + w * 256);
  }

  f32x4 minv[8];
#pragma unroll
  for (int Mt = 0; Mt < 8; ++Mt)
#pragma unroll
    for (int q = 0; q < 4; ++q) minv[Mt][q] = 3.0e38f;

  for (int t = 0; t < 128; ++t) {
    // wait for tile t's 5 ops (t+1, t+2's 10 remain in flight); never drain to 0
    asm volatile("s_waitcnt vmcnt(10)" ::: "memory");
    __builtin_amdgcn_sched_barrier(0);

    const char* cur = smem + (t & 3) * 32768;
    ulongx2 bv[4];
#pragma unroll
    for (int ksp = 0; ksp < 4; ++ksp)
      bv[ksp] = *(const ulongx2*)(cur + n0 * 256 + ((lk * 64 + ksp * 16) ^ rswz));
    const float m2c = *(const float*)(smem + 131072 + (t & 3) * 2048 + w * 256 + lr * 4);

    // stage tile t+3 into the ring slot whose reads finished last iteration
    {
      const int tn = t + 3;
      char* db = smem + (tn & 3) * 32768 + w * 4096;
#pragma unroll
      for (int i = 0; i < 4; ++i)
        GLL(BB8 + ((size_t)tn * 128 + (w * 4 + i) * 4 + lk) * 256 + lr * 16, db + i * 1024);
      GLL4(m2g + tn * 128 + w * 16 + lr, smem + 131072 + (tn & 3) * 2048 + w * 256);
    }

    // acc starts at m2[col]; BB8 = -2*bank, so acc ends at m2 - 2*<proj,bank>
    f32x4 acc[8];
#pragma unroll
    for (int Mt = 0; Mt < 8; ++Mt)
#pragma unroll
      for (int q = 0; q < 4; ++q) acc[Mt][q] = m2c;

    __builtin_amdgcn_s_setprio(1);
#pragma unroll
    for (int ksp = 0; ksp < 4; ++ksp) {
#pragma unroll
      for (int Mt = 0; Mt < 8; ++Mt) acc[Mt] = MFMA8(A[Mt][2 * ksp], bv[ksp].x, acc[Mt]);
#pragma unroll
      for (int Mt = 0; Mt < 8; ++Mt) acc[Mt] = MFMA8(A[Mt][2 * ksp + 1], bv[ksp].y, acc[Mt]);
    }
    __builtin_amdgcn_s_setprio(0);

#pragma unroll
    for (int Mt = 0; Mt < 8; ++Mt)
#pragma unroll
      for (int q = 0; q < 4; ++q) minv[Mt][q] = fminf(minv[Mt][q], acc[Mt][q]);
  }

  // reduce min over the 16 bank-column lanes (lr); rows live at lk*4+q
#pragma unroll
  for (int Mt = 0; Mt < 8; ++Mt)
#pragma unroll
    for (int q = 0; q < 4; ++q) {
      float v = minv[Mt][q];
      v = fminf(v, __shfl_xor(v, 1)); v = fminf(v, __shfl_xor(v, 2));
      v = fminf(v, __shfl_xor(v, 4)); v = fminf(v, __shfl_xor(v, 8));
      minv[Mt][q] = v;
    }
  if (lr == 0) {
#pragma unroll
    for (int Mt = 0; Mt < 8; ++Mt)
#pragma unroll
      for (int q = 0; q < 4; ++q)
        minbuf[w * 128 + Mt * 16 + lk * 4 + q] = minv[Mt][q];
  }
  __syncthreads();
  if (tid < 128) {
    float m = minbuf[tid];
#pragma unroll
    for (int v = 1; v < 8; ++v) m = fminf(m, minbuf[v * 128 + tid]);
    const float d2 = X2[r0 + tid] + m;
    out[r0 + tid] = sqrtf(fmaxf(d2, 0.f));
  }
}

extern "C" void kernel_launch(void* const* d_in, const int* in_sizes, int n_in,
                              void* d_out, int out_size, void* d_ws, size_t ws_size,
                              hipStream_t stream) {
  const float* F = (const float*)d_in[0];
  const float* W1 = (const float*)d_in[1];
  const float* b1 = (const float*)d_in[2];
  const float* W2 = (const float*)d_in[3];
  const float* b2 = (const float*)d_in[4];
  const float* bank = (const float*)d_in[5];
  float* out = (float*)d_out;

  char* ws = (char*)d_ws;
  unsigned char* BB8 = (unsigned char*)(ws + 0);   // 4,194,304 B + 131,072 pad (3 dummy tiles)
  float* m2 = (float*)(ws + 4325376);              //    65,536 B +   4,096 pad
  bf16* W1t = (bf16*)(ws + 4395008);               // 1,048,576 B
  bf16* W2t = (bf16*)(ws + 5443584);               //   262,144 B
  bf16* H = (bf16*)(ws + 5705728);                 // 33,554,432 B
  unsigned char* PROJ8 = (unsigned char*)(ws + 39260160);  // 8,388,608 B
  float* X2 = (float*)(ws + 47648768);             //   131,072 B -> total 47,779,840 B

  prep_w<<<2560, 256, 0, stream>>>(W1, W2, W1t, W2t);
  prep_bank<<<4096, 256, 0, stream>>>(bank, BB8, m2);
  mlp1_kernel<<<256, 512, 0, stream>>>(F, W1t, b1, H);
  mlp2_kernel<<<256, 512, 0, stream>>>(H, W2t, b2, PROJ8, X2);
  dist_kernel<<<256, 512, 0, stream>>>(PROJ8, BB8, m2, X2, out);
}

// Round 7
// 209.335 us; speedup vs baseline: 1.6592x; 1.2419x over previous
//
#include <hip/hip_runtime.h>
#include <math.h>

typedef __bf16 bf16;
typedef __attribute__((ext_vector_type(8))) __bf16 bf16x8;
typedef __attribute__((ext_vector_type(4))) float f32x4;
typedef __attribute__((ext_vector_type(8))) int i32x8;

typedef __attribute__((address_space(1))) const void gvoid;
typedef __attribute__((address_space(3))) void lvoid;
#define GLL(g, l) __builtin_amdgcn_global_load_lds((gvoid*)(g), (lvoid*)(l), 16, 0, 0)
#define MFMA(a, b, c) __builtin_amdgcn_mfma_f32_16x16x32_bf16((a), (b), (c), 0, 0, 0)
// MX-scaled fp8 GEMM, unit scales (E8M0 0x7F = 1.0): exact same math as fp8_fp8, 2.28x rate
#define MFMAS(a, b, c) \
  __builtin_amdgcn_mfma_scale_f32_16x16x128_f8f6f4((a), (b), (c), 0, 0, 0, 0x7F, 0, 0x7F)

__device__ __forceinline__ int swz128(int row, int kb) { return kb ^ ((row & 7) << 4); }

// ---- fp8 e4m3fn encode/decode (OCP: bias 7, max 448, no inf) ----
__device__ __forceinline__ unsigned char f32_to_e4m3(float x) {
  const unsigned s = (__float_as_uint(x) >> 24) & 0x80;
  float ax = fminf(fabsf(x), 448.f);
  unsigned e;
  if (ax >= 0.015625f) {  // normal range (>= 2^-6)
    const unsigned u = __float_as_uint(ax);
    const unsigned t = u + 0x7FFFF + ((u >> 20) & 1);  // RNE to 3 mantissa bits
    e = (((t >> 23) - 120) << 3) | ((t >> 20) & 7);
  } else {  // subnormal: value = q * 2^-9, q in 0..8
    e = (unsigned)__float2int_rn(ax * 512.f);
  }
  return (unsigned char)(s | e);
}
__device__ __forceinline__ float e4m3_to_f32(unsigned char b) {
  const unsigned s = ((unsigned)b & 0x80) << 24;
  const unsigned em = b & 0x7F;
  float v;
  if (em >= 8) v = __uint_as_float((((em >> 3) + 120) << 23) | ((em & 7) << 20));
  else v = (float)em * 0.001953125f;
  return __uint_as_float(__float_as_uint(v) | s);
}

// ---------------- prep: W1 [1024][512] -> W1t bf16 [512][1024]; W2 [512][256] -> W2t [256][512]
__global__ __launch_bounds__(256) void prep_w(const float* __restrict__ W1,
                                              const float* __restrict__ W2,
                                              bf16* __restrict__ W1t, bf16* __restrict__ W2t) {
  const int t = blockIdx.x * 256 + threadIdx.x;
  if (t < 512 * 1024) {
    const int h = t & 511, k = t >> 9;
    W1t[h * 1024 + k] = (bf16)W1[k * 512 + h];
  } else {
    const int u = t - 512 * 1024;
    const int e = u & 255, k = u >> 8;
    W2t[e * 512 + k] = (bf16)W2[k * 256 + e];
  }
}

// ---------------- prep: bank fp32 [16384][256] -> SB8 = e4m3(-2*bank) repacked as a
// per-(tile, wave, half, lane) register-fragment stream:
//   SB8[(((t*8+w)*2+h)*64 + lk*16 + lr)*32 + (k & 31)]  holds bank row (t*128+w*16+lr),
//   k = h*128 + lk*32 + [0,32)  -- one i32x8 load per lane per half, fully coalesced.
// m2[row] consistent with the quantized values used in MFMA.
__global__ __launch_bounds__(256) void prep_bank(const float* __restrict__ bank,
                                                 unsigned char* __restrict__ SB8,
                                                 float* __restrict__ m2) {
  const int tid = threadIdx.x, lane = tid & 63, wv = tid >> 6;
  const int row = blockIdx.x * 4 + wv;
  const float4 v = *reinterpret_cast<const float4*>(bank + (size_t)row * 256 + lane * 4);
  uchar4 q;
  float ssum = 0.f;
  {
    const float xs[4] = {v.x, v.y, v.z, v.w};
    unsigned char qb[4];
#pragma unroll
    for (int e = 0; e < 4; ++e) {
      qb[e] = f32_to_e4m3(-2.f * xs[e]);
      const float d = e4m3_to_f32(qb[e]);
      ssum += d * d;
    }
    q.x = qb[0]; q.y = qb[1]; q.z = qb[2]; q.w = qb[3];
  }
#pragma unroll
  for (int off = 1; off < 64; off <<= 1) ssum += __shfl_xor(ssum, off);
  // k0 = lane*4: h = k0>>7, lk = (k0>>5)&3, off32 = k0&31
  const int t = row >> 7, ww = (row >> 4) & 7, lrr = row & 15;
  const int h = lane >> 5, lk = (lane >> 3) & 3, off32 = (lane & 7) * 4;
  const size_t dst = ((((size_t)t * 8 + ww) * 2 + h) * 64 + lk * 16 + lrr) * 32 + off32;
  *reinterpret_cast<uchar4*>(SB8 + dst) = q;
  if (lane == 0) m2[row] = ssum * 0.25f;  // (d/2)^2 summed
}

// ---------------- mlp1: H[32768][512] = relu(F @ W1 + b1), bf16 out
__global__ __launch_bounds__(512, 2) void mlp1_kernel(const float* __restrict__ F,
                                                      const bf16* __restrict__ W1t,
                                                      const float* __restrict__ b1,
                                                      bf16* __restrict__ H) {
  __shared__ __align__(16) char smem[81920];
  char* sA = smem;          // F chunk bf16 [128 rows][128B], swizzled
  char* sB = smem + 16384;  // W1t chunk [512 n][128B], swizzled

  const int tid = threadIdx.x;
  const int w = tid >> 6, lane = tid & 63;
  const int wm = w >> 2, wn = w & 3;
  const int lr = lane & 15, lk = lane >> 4;
  const size_t r0 = (size_t)blockIdx.x * 128;

  f32x4 acc[4][8];
  const f32x4 z = {0.f, 0.f, 0.f, 0.f};
#pragma unroll
  for (int m = 0; m < 4; ++m)
#pragma unroll
    for (int n = 0; n < 8; ++n) acc[m][n] = z;

  for (int kc = 0; kc < 16; ++kc) {
    {
      const int fr = tid >> 2, kg = (tid & 3) << 4;
      const float* fsrc = F + (r0 + fr) * 1024 + kc * 64 + kg;
      const float4 f0 = *reinterpret_cast<const float4*>(fsrc);
      const float4 f1 = *reinterpret_cast<const float4*>(fsrc + 4);
      const float4 f2 = *reinterpret_cast<const float4*>(fsrc + 8);
      const float4 f3 = *reinterpret_cast<const float4*>(fsrc + 12);
      bf16x8 p0, p1;
      p0[0] = (bf16)f0.x; p0[1] = (bf16)f0.y; p0[2] = (bf16)f0.z; p0[3] = (bf16)f0.w;
      p0[4] = (bf16)f1.x; p0[5] = (bf16)f1.y; p0[6] = (bf16)f1.z; p0[7] = (bf16)f1.w;
      p1[0] = (bf16)f2.x; p1[1] = (bf16)f2.y; p1[2] = (bf16)f2.z; p1[3] = (bf16)f2.w;
      p1[4] = (bf16)f3.x; p1[5] = (bf16)f3.y; p1[6] = (bf16)f3.z; p1[7] = (bf16)f3.w;
      const int bb = kg * 2;
      *(bf16x8*)(sA + fr * 128 + swz128(fr, bb)) = p0;
      *(bf16x8*)(sA + fr * 128 + swz128(fr, bb + 16)) = p1;
    }
#pragma unroll
    for (int i = 0; i < 8; ++i) {
      const int o = (w * 8 + i) * 1024 + lane * 16;
      const int n = o >> 7, b = o & 127;
      GLL((const char*)W1t + n * 2048 + kc * 128 + swz128(n, b), sB + (w * 8 + i) * 1024);
    }
    __syncthreads();
#pragma unroll
    for (int ks = 0; ks < 2; ++ks) {
      bf16x8 av[4];
#pragma unroll
      for (int Mt = 0; Mt < 4; ++Mt) {
        const int row = wm * 64 + Mt * 16 + lr;
        av[Mt] = *(const bf16x8*)(sA + row * 128 + swz128(row, ks * 64 + lk * 16));
      }
#pragma unroll
      for (int Nt = 0; Nt < 8; ++Nt) {
        const int n = wn * 128 + Nt * 16 + lr;
        const bf16x8 bv = *(const bf16x8*)(sB + n * 128 + swz128(n, ks * 64 + lk * 16));
#pragma unroll
        for (int Mt = 0; Mt < 4; ++Mt) acc[Mt][Nt] = MFMA(av[Mt], bv, acc[Mt][Nt]);
      }
    }
    __syncthreads();
  }
#pragma unroll
  for (int Nt = 0; Nt < 8; ++Nt) {
    const int col = wn * 128 + Nt * 16 + lr;
    const float bias = b1[col];
#pragma unroll
    for (int Mt = 0; Mt < 4; ++Mt) {
      const size_t rowb = r0 + wm * 64 + Mt * 16 + lk * 4;
#pragma unroll
      for (int q = 0; q < 4; ++q)
        H[(rowb + q) * 512 + col] = (bf16)fmaxf(acc[Mt][Nt][q] + bias, 0.f);
    }
  }
}

// ---------------- mlp2: PROJ8[32768][256] fp8 = e4m3(H @ W2 + b2); X2 from decoded fp8
__global__ __launch_bounds__(512, 2) void mlp2_kernel(const bf16* __restrict__ H,
                                                      const bf16* __restrict__ W2t,
                                                      const float* __restrict__ b2,
                                                      unsigned char* __restrict__ PROJ8,
                                                      float* __restrict__ X2) {
  __shared__ __align__(16) char smem[51200];
  char* sA = smem;                        // H chunk [128][128B] swizzled
  char* sB = smem + 16384;                // W2t chunk [256][128B] swizzled
  float* sX2 = (float*)(smem + 49152);    // [4][128]

  const int tid = threadIdx.x;
  const int w = tid >> 6, lane = tid & 63;
  const int wm = w >> 2, wn = w & 3;
  const int lr = lane & 15, lk = lane >> 4;
  const size_t r0 = (size_t)blockIdx.x * 128;

  f32x4 acc[4][4];
  const f32x4 z = {0.f, 0.f, 0.f, 0.f};
#pragma unroll
  for (int m = 0; m < 4; ++m)
#pragma unroll
    for (int n = 0; n < 4; ++n) acc[m][n] = z;

  for (int kc = 0; kc < 8; ++kc) {
#pragma unroll
    for (int i = 0; i < 2; ++i) {
      const int o = (w * 2 + i) * 1024 + lane * 16;
      const int row = o >> 7, b = o & 127;
      GLL((const char*)H + (r0 + row) * 1024 + kc * 128 + swz128(row, b), sA + (w * 2 + i) * 1024);
    }
#pragma unroll
    for (int i = 0; i < 4; ++i) {
      const int o = (w * 4 + i) * 1024 + lane * 16;
      const int n = o >> 7, b = o & 127;
      GLL((const char*)W2t + n * 1024 + kc * 128 + swz128(n, b), sB + (w * 4 + i) * 1024);
    }
    __syncthreads();
#pragma unroll
    for (int ks = 0; ks < 2; ++ks) {
      bf16x8 av[4];
#pragma unroll
      for (int Mt = 0; Mt < 4; ++Mt) {
        const int row = wm * 64 + Mt * 16 + lr;
        av[Mt] = *(const bf16x8*)(sA + row * 128 + swz128(row, ks * 64 + lk * 16));
      }
#pragma unroll
      for (int Nt = 0; Nt < 4; ++Nt) {
        const int n = wn * 64 + Nt * 16 + lr;
        const bf16x8 bv = *(const bf16x8*)(sB + n * 128 + swz128(n, ks * 64 + lk * 16));
#pragma unroll
        for (int Mt = 0; Mt < 4; ++Mt) acc[Mt][Nt] = MFMA(av[Mt], bv, acc[Mt][Nt]);
      }
    }
    __syncthreads();
  }
  // epilogue: +b2, quantize to fp8, store PROJ8, accumulate consistent x2
  float x2p[4][4];
#pragma unroll
  for (int m = 0; m < 4; ++m)
#pragma unroll
    for (int q = 0; q < 4; ++q) x2p[m][q] = 0.f;
#pragma unroll
  for (int Nt = 0; Nt < 4; ++Nt) {
    const int col = wn * 64 + Nt * 16 + lr;
    const float bias = b2[col];
#pragma unroll
    for (int Mt = 0; Mt < 4; ++Mt) {
      const size_t rowb = r0 + wm * 64 + Mt * 16 + lk * 4;
#pragma unroll
      for (int q = 0; q < 4; ++q) {
        const float p = acc[Mt][Nt][q] + bias;
        const unsigned char qb = f32_to_e4m3(p);
        PROJ8[(rowb + q) * 256 + col] = qb;
        const float d = e4m3_to_f32(qb);
        x2p[Mt][q] += d * d;
      }
    }
  }
#pragma unroll
  for (int Mt = 0; Mt < 4; ++Mt)
#pragma unroll
    for (int q = 0; q < 4; ++q) {
      float v = x2p[Mt][q];
      v += __shfl_xor(v, 1); v += __shfl_xor(v, 2);
      v += __shfl_xor(v, 4); v += __shfl_xor(v, 8);
      x2p[Mt][q] = v;
    }
  __syncthreads();
  if (lr == 0) {
#pragma unroll
    for (int Mt = 0; Mt < 4; ++Mt)
#pragma unroll
      for (int q = 0; q < 4; ++q)
        sX2[wn * 128 + wm * 64 + Mt * 16 + lk * 4 + q] = x2p[Mt][q];
  }
  __syncthreads();
  if (tid < 128)
    X2[r0 + tid] = sX2[tid] + sX2[128 + tid] + sX2[256 + tid] + sX2[384 + tid];
}

// ---------------- dist (MX-fp8, LDS-free): B fragments stream L2 -> registers directly
// (SB8 is the repacked fragment stream; 4MB, XCD-L2-resident). 16x16x128 scaled MFMA
// with unit scales. Double-buffered regs, unroll-2, no barriers in the main loop.
__global__ __launch_bounds__(512, 2) void dist_kernel(const unsigned char* __restrict__ PROJ8,
                                                      const unsigned char* __restrict__ SB8,
                                                      const float* __restrict__ m2g,
                                                      const float* __restrict__ X2,
                                                      float* __restrict__ out) {
  __shared__ float minbuf[1024];

  const int tid = threadIdx.x;
  const int w = tid >> 6, lane = tid & 63;
  const int lr = lane & 15, lk = lane >> 4;
  const size_t r0 = (size_t)blockIdx.x * 128;

  // A fragments: A[Mt][h] = 32 fp8 of proj row (r0+Mt*16+lr), k = h*128 + lk*32 .. +32
  i32x8 A[8][2];
#pragma unroll
  for (int Mt = 0; Mt < 8; ++Mt)
#pragma unroll
    for (int h = 0; h < 2; ++h)
      A[Mt][h] = *(const i32x8*)(PROJ8 + (r0 + Mt * 16 + lr) * 256 + h * 128 + lk * 32);

  const char* sb = (const char*)SB8 + ((size_t)w * 2 * 64 + lane) * 32;  // + t*32768, h*2048
  const float* m2p = m2g + w * 16 + lr;                                  // + t*128

  f32x4 minv[8];
#pragma unroll
  for (int Mt = 0; Mt < 8; ++Mt)
#pragma unroll
    for (int q = 0; q < 4; ++q) minv[Mt][q] = 3.0e38f;

#define COMPUTE(B0, B1, MC)                                                       \
  do {                                                                            \
    f32x4 acc[8];                                                                 \
    _Pragma("unroll") for (int Mt = 0; Mt < 8; ++Mt) {                            \
      acc[Mt][0] = (MC); acc[Mt][1] = (MC); acc[Mt][2] = (MC); acc[Mt][3] = (MC); \
    }                                                                             \
    __builtin_amdgcn_s_setprio(1);                                                \
    _Pragma("unroll") for (int Mt = 0; Mt < 8; ++Mt)                              \
      acc[Mt] = MFMAS(A[Mt][0], (B0), acc[Mt]);                                   \
    _Pragma("unroll") for (int Mt = 0; Mt < 8; ++Mt)                              \
      acc[Mt] = MFMAS(A[Mt][1], (B1), acc[Mt]);                                   \
    __builtin_amdgcn_s_setprio(0);                                                \
    _Pragma("unroll") for (int Mt = 0; Mt < 8; ++Mt) {                            \
      minv[Mt][0] = fminf(minv[Mt][0], acc[Mt][0]);                               \
      minv[Mt][1] = fminf(minv[Mt][1], acc[Mt][1]);                               \
      minv[Mt][2] = fminf(minv[Mt][2], acc[Mt][2]);                               \
      minv[Mt][3] = fminf(minv[Mt][3], acc[Mt][3]);                               \
    }                                                                             \
  } while (0)

  // prologue: tile 0 into buffer A
  i32x8 bA0 = *(const i32x8*)(sb);
  i32x8 bA1 = *(const i32x8*)(sb + 2048);
  float mA = m2p[0];
  i32x8 bB0, bB1;
  float mB;

  for (int t = 0; t < 128; t += 2) {
    // issue tile t+1 loads, then compute tile t (loads hide under MFMA)
    bB0 = *(const i32x8*)(sb + (size_t)(t + 1) * 32768);
    bB1 = *(const i32x8*)(sb + (size_t)(t + 1) * 32768 + 2048);
    mB = m2p[(t + 1) * 128];
    __builtin_amdgcn_sched_barrier(0);
    COMPUTE(bA0, bA1, mA);
    // issue tile t+2 loads, then compute tile t+1
    bA0 = *(const i32x8*)(sb + (size_t)(t + 2) * 32768);
    bA1 = *(const i32x8*)(sb + (size_t)(t + 2) * 32768 + 2048);
    mA = m2p[(t + 2) * 128];
    __builtin_amdgcn_sched_barrier(0);
    COMPUTE(bB0, bB1, mB);
  }
#undef COMPUTE

  // reduce min over the 16 bank-column lanes (lr); rows live at lk*4+q
#pragma unroll
  for (int Mt = 0; Mt < 8; ++Mt)
#pragma unroll
    for (int q = 0; q < 4; ++q) {
      float v = minv[Mt][q];
      v = fminf(v, __shfl_xor(v, 1)); v = fminf(v, __shfl_xor(v, 2));
      v = fminf(v, __shfl_xor(v, 4)); v = fminf(v, __shfl_xor(v, 8));
      minv[Mt][q] = v;
    }
  if (lr == 0) {
#pragma unroll
    for (int Mt = 0; Mt < 8; ++Mt)
#pragma unroll
      for (int q = 0; q < 4; ++q)
        minbuf[w * 128 + Mt * 16 + lk * 4 + q] = minv[Mt][q];
  }
  __syncthreads();
  if (tid < 128) {
    float m = minbuf[tid];
#pragma unroll
    for (int v = 1; v < 8; ++v) m = fminf(m, minbuf[v * 128 + tid]);
    const float d2 = X2[r0 + tid] + m;
    out[r0 + tid] = sqrtf(fmaxf(d2, 0.f));
  }
}

extern "C" void kernel_launch(void* const* d_in, const int* in_sizes, int n_in,
                              void* d_out, int out_size, void* d_ws, size_t ws_size,
                              hipStream_t stream) {
  const float* F = (const float*)d_in[0];
  const float* W1 = (const float*)d_in[1];
  const float* b1 = (const float*)d_in[2];
  const float* W2 = (const float*)d_in[3];
  const float* b2 = (const float*)d_in[4];
  const float* bank = (const float*)d_in[5];
  float* out = (float*)d_out;

  char* ws = (char*)d_ws;
  unsigned char* SB8 = (unsigned char*)(ws + 0);   // 4,194,304 B + 65,536 pad (2 dummy tiles)
  float* m2 = (float*)(ws + 4259840);              //    65,536 B +  1,024 pad
  bf16* W1t = (bf16*)(ws + 4326400);               // 1,048,576 B
  bf16* W2t = (bf16*)(ws + 5374976);               //   262,144 B
  bf16* H = (bf16*)(ws + 5637120);                 // 33,554,432 B
  unsigned char* PROJ8 = (unsigned char*)(ws + 39191552);  // 8,388,608 B
  float* X2 = (float*)(ws + 47580160);             //   131,072 B -> total 47,711,232 B

  prep_w<<<2560, 256, 0, stream>>>(W1, W2, W1t, W2t);
  prep_bank<<<4096, 256, 0, stream>>>(bank, SB8, m2);
  mlp1_kernel<<<256, 512, 0, stream>>>(F, W1t, b1, H);
  mlp2_kernel<<<256, 512, 0, stream>>>(H, W2t, b2, PROJ8, X2);
  dist_kernel<<<256, 512, 0, stream>>>(PROJ8, SB8, m2, X2, out);
}